// Round 4
// baseline (458.376 us; speedup 1.0000x reference)
//
#include <hip/hip_runtime.h>
#include <math.h>

typedef __attribute__((ext_vector_type(8))) short short8;
typedef __attribute__((ext_vector_type(4))) float f32x4;
typedef __attribute__((ext_vector_type(16))) float f32x16;
typedef unsigned short u16;
typedef unsigned int u32;
typedef __attribute__((ext_vector_type(2))) u32 u32x2;
typedef __attribute__((ext_vector_type(4))) u32 u32x4;
typedef unsigned long long u64;

static constexpr int E = 1024, H = 16, LQ = 1024, LC = 512, Bn = 4, FF = 4096;
static constexpr int NTOK = Bn * LQ;   // 4096
static constexpr int NCTX = Bn * LC;   // 2048

// Q pre-scale: 1/sqrt(64) * log2(e)  (softmax runs in exp2 domain)
#define QSCALE 0.1803368801111244f
#define DEFER_THR 11.5f

// ---------------- workspace layout (bytes) ----------------
static constexpr size_t OFF_TCOS   = 0;                                    // 1024*32 f32
static constexpr size_t OFF_TSIN   = OFF_TCOS + (size_t)LQ*32*4;
static constexpr size_t OFF_BSAQKV = OFF_TSIN + (size_t)LQ*32*4;           // 3072 f32 (+ca_k/v bias after)
static constexpr size_t OFF_BCAKV  = OFF_BSAQKV + 16384;                   // 2048 f32
// contiguous bf16 weight region (order matters for cvt_all):
static constexpr size_t OFF_WSAQKV = OFF_BCAKV + 16384;                    // [3072][1024] bf16
static constexpr size_t OFF_WSAP   = OFF_WSAQKV + (size_t)3072*1024*2;     // [1024][1024]
static constexpr size_t OFF_WCAQ   = OFF_WSAP   + (size_t)1024*1024*2;
static constexpr size_t OFF_WCAKV  = OFF_WCAQ   + (size_t)1024*1024*2;     // [2048][1024]
static constexpr size_t OFF_WCAP   = OFF_WCAKV  + (size_t)2048*1024*2;
static constexpr size_t OFF_WFC1   = OFF_WCAP   + (size_t)1024*1024*2;     // [4096][1024]
static constexpr size_t OFF_WFC2   = OFF_WFC1   + (size_t)4096*1024*2;     // [1024][4096]
static constexpr size_t OFF_CTXB   = OFF_WFC2   + (size_t)1024*4096*2;     // [2048][1024] bf16
static constexpr size_t OFF_H      = OFF_CTXB   + (size_t)2048*1024*2;     // [4096][1024] bf16 (LN out)
static constexpr size_t OFF_QKV    = OFF_H      + (size_t)4096*1024*2;     // [4096][3072] bf16
static constexpr size_t OFF_CAQ    = OFF_QKV;                              // [4096][1024]
static constexpr size_t OFF_CAKV   = OFF_QKV + (size_t)4096*1024*2;        // [2048][2048]
static constexpr size_t OFF_QR     = OFF_QKV + (size_t)4096*3072*2;        // [B,H,LQ,64]
static constexpr size_t OFF_KR     = OFF_QR  + (size_t)4096*1024*2;        // [B,H,Lk,64]
static constexpr size_t OFF_VT     = OFF_KR  + (size_t)4096*1024*2;        // [B,H,64,Lk]
static constexpr size_t OFF_AO     = OFF_VT  + (size_t)4096*1024*2;        // [4096][1024] bf16
static constexpr size_t OFF_U      = OFF_QKV;                              // fc1 out [4096][4096] bf16 reuses QKV+QR
static constexpr size_t WS_NEED    = OFF_AO + (size_t)4096*1024*2;         // ~105 MB

// ---------------- helpers ----------------
static __device__ __forceinline__ float bf2f(u16 u) {
  union { u32 i; float f; } un; un.i = ((u32)u) << 16; return un.f;
}
static __device__ __forceinline__ u16 f2bf(float f) {  // RNE
  union { float f; u32 u; } un; un.f = f;
  u32 u = un.u;
  return (u16)((u + 0x7FFFu + ((u >> 16) & 1u)) >> 16);
}
static __device__ __forceinline__ u64 pack4(u16 a, u16 b, u16 c, u16 d) {
  return (u64)a | ((u64)b << 16) | ((u64)c << 32) | ((u64)d << 48);
}
static __device__ __forceinline__ f32x4 mfma16(short8 a, short8 b, f32x4 c) {
  return __builtin_amdgcn_mfma_f32_16x16x32_bf16(a, b, c, 0, 0, 0);
}
static __device__ __forceinline__ f32x16 mfma32(short8 a, short8 b, f32x16 c) {
  return __builtin_amdgcn_mfma_f32_32x32x16_bf16(a, b, c, 0, 0, 0);
}
static __device__ __forceinline__ void gload_lds16(void* lds, const void* g) {
  __builtin_amdgcn_global_load_lds(
      (const __attribute__((address_space(1))) void*)g,
      (__attribute__((address_space(3))) void*)lds, 16, 0, 0);
}
static __device__ __forceinline__ float gelu_tanh(float x) {
  float t = tanhf(0.7978845608028654f * (x + 0.044715f * x * x * x));
  return 0.5f * x * (1.0f + t);
}
static __device__ __forceinline__ u32 cvtpk_bf16(float lo, float hi) {
  u32 r;
  asm("v_cvt_pk_bf16_f32 %0, %1, %2" : "=v"(r) : "v"(lo), "v"(hi));
  return r;
}
#define VMCNT(n) asm volatile("s_waitcnt vmcnt(" #n ")" ::: "memory")
#define SBAR() __builtin_amdgcn_s_barrier()

// ---------------- small kernels ----------------
__global__ __launch_bounds__(256) void build_tab(float* __restrict__ ct, float* __restrict__ st) {
  int idx = blockIdx.x * 256 + threadIdx.x;           // 1024*32 entries
  int pos = idx >> 5, i = idx & 31;
  float inv = powf(10000.f, -(float)i * (1.f / 32.f));
  float a = (float)pos * inv;
  ct[idx] = cosf(a);
  st[idx] = sinf(a);
}

// fused fp32->bf16 conversion of all weights + context into the contiguous
// bf16 ws region. 11 segments, sizes (in 4-elem units): 8 x 262144, 2 x 1048576, 524288.
struct Cvt11 { const float* s[11]; };
__global__ __launch_bounds__(256) void cvt_all(Cvt11 a, u16* __restrict__ dst) {
  u32 gid = blockIdx.x * 256 + threadIdx.x;   // 0 .. 4718591
  u32 s, off;
  if (gid < 2097152u)      { s = gid >> 18;                        off = gid & 262143u; }
  else if (gid < 4194304u) { u32 t = gid - 2097152u; s = 8 + (t >> 20); off = t & 1048575u; }
  else                     { s = 10;                               off = gid - 4194304u; }
  float4 v = *(const float4*)(a.s[s] + (size_t)off * 4);
  *(u64*)(dst + (size_t)gid * 4) = pack4(f2bf(v.x), f2bf(v.y), f2bf(v.z), f2bf(v.w));
}

// fused bias copies: sa_q,sa_k,sa_v -> BSAQKV(+0,+1024,+2048); ca_k,ca_v -> BCAKV(+0,+1024)
struct Cp5 { const float* s[5]; };
__global__ __launch_bounds__(256) void copy5(Cp5 a, float* __restrict__ dst) {
  int gid = blockIdx.x * 256 + threadIdx.x;   // 0..5119
  int s = gid >> 10, off = gid & 1023;
  int doff = (s < 3) ? s * 1024 : 4096 + (s - 3) * 1024;
  dst[doff + off] = a.s[s][off];
}

// out[row][c] += gate[c]*bias[c]  (init pass for split-K atomic GEMM)
__global__ __launch_bounds__(256) void init_bias_gate(float* __restrict__ out, const float* __restrict__ bias,
                                                      const float* __restrict__ gate) {
  int i = (blockIdx.x * 256 + threadIdx.x) * 4;
  int c = i & 1023;
  float4 o = *(float4*)(out + i);
  o.x += gate[c] * bias[c];
  o.y += gate[c + 1] * bias[c + 1];
  o.z += gate[c + 2] * bias[c + 2];
  o.w += gate[c + 3] * bias[c + 3];
  *(float4*)(out + i) = o;
}

// LN over last dim 1024, one row per block (256 threads, 4 f32 each), bf16 out.
__global__ __launch_bounds__(256) void ln_bf16(const float* __restrict__ x, const float* __restrict__ w,
                                               const float* __restrict__ b, u16* __restrict__ out) {
  __shared__ float red[4];
  int row = blockIdx.x, tid = threadIdx.x;
  const float* xr = x + (size_t)row * 1024;
  float4 v = ((const float4*)xr)[tid];
  float s = v.x + v.y + v.z + v.w;
#pragma unroll
  for (int off = 32; off; off >>= 1) s += __shfl_xor(s, off);
  if ((tid & 63) == 0) red[tid >> 6] = s;
  __syncthreads();
  float mean = (red[0] + red[1] + red[2] + red[3]) * (1.f / 1024.f);
  float dx = v.x - mean, dy = v.y - mean, dz = v.z - mean, dw = v.w - mean;
  float sq = dx * dx + dy * dy + dz * dz + dw * dw;
#pragma unroll
  for (int off = 32; off; off >>= 1) sq += __shfl_xor(sq, off);
  __syncthreads();
  if ((tid & 63) == 0) red[tid >> 6] = sq;
  __syncthreads();
  float var = (red[0] + red[1] + red[2] + red[3]) * (1.f / 1024.f);
  float rstd = rsqrtf(var + 1e-6f);
  float4 wv = ((const float4*)w)[tid];
  float4 bv = ((const float4*)b)[tid];
  u64 o = pack4(f2bf(dx * rstd * wv.x + bv.x), f2bf(dy * rstd * wv.y + bv.y),
                f2bf(dz * rstd * wv.z + bv.z), f2bf(dw * rstd * wv.w + bv.w));
  *(u64*)(out + (size_t)row * 1024 + tid * 4) = o;
}

// RoPE + layout scatter. src [T][ld] bf16 (+col0), 128 threads x 8 elems per token.
template <int ROPE, int TRANS>
__global__ __launch_bounds__(128) void rope_scatter(const u16* __restrict__ src, int ld, int col0,
                                                    u16* __restrict__ dst,
                                                    const float* __restrict__ cosT,
                                                    const float* __restrict__ sinT, int Lper,
                                                    float scale) {
  int t = blockIdx.x;
  int b = t / Lper, l = t - b * Lper;
  int tid = threadIdx.x;
  int e0 = tid * 8;
  int h = e0 >> 6, d0 = e0 & 63;
  short8 vv = *(const short8*)(src + (size_t)t * ld + col0 + e0);
  if (ROPE) {
    short8 ov;
#pragma unroll
    for (int j = 0; j < 4; ++j) {
      float x1 = bf2f((u16)vv[2 * j]);
      float x2 = bf2f((u16)vv[2 * j + 1]);
      int i = (d0 >> 1) + j;
      float c = cosT[l * 32 + i], s = sinT[l * 32 + i];
      ov[2 * j]     = (short)f2bf((x1 * c - x2 * s) * scale);
      ov[2 * j + 1] = (short)f2bf((x1 * s + x2 * c) * scale);
    }
    *(short8*)(dst + (((size_t)b * H + h) * Lper + l) * 64 + d0) = ov;
  } else if (TRANS) {
#pragma unroll
    for (int m = 0; m < 8; ++m)
      dst[(((size_t)b * H + h) * 64 + d0 + m) * Lper + l] = (u16)vv[m];
  }
}

// ---------------- GEMM kernels: C[M,N] = A[M,K] @ W[N,K]^T + bias ----------------
enum { EPI_BF16 = 0, EPI_GELU = 1, EPI_RESID = 2, EPI_ATOMIC = 3 };

// gemm2: 128x128 tile, 512 threads, 2-phase dbuf (proven). For N<=2048 GEMMs.
template <int EPI>
__global__ __launch_bounds__(512, 4) void gemm2(const u16* __restrict__ A, const u16* __restrict__ W,
                                                const float* __restrict__ bias, u16* outb, float* outf,
                                                const float* res, const float* __restrict__ gate,
                                                int M, int N, int K, int kchunks) {
  __shared__ u16 As[2][128 * 64];
  __shared__ u16 Bs[2][128 * 64];

  int nwg = gridDim.x * gridDim.y;
  int bid = blockIdx.y * gridDim.x + blockIdx.x;
  int cpx = nwg >> 3;
  int swz = (bid & 7) * cpx + (bid >> 3);
  int bx = swz % gridDim.x;
  int by = swz / gridDim.x;
  int row0 = by * 128, col0 = bx * 128;

  const int Kc = K / kchunks;
  const int kbase = blockIdx.z * Kc;

  int tid = threadIdx.x;
  int lane = tid & 63, wid = tid >> 6;
  int wr = wid >> 2, wc = wid & 3;  // 2x4 waves, each owns 64x32
  int lr = lane & 15, lg = lane >> 4;

  size_t a_off0, a_off1, b_off0, b_off1;
  int l_off0 = tid * 8, l_off1 = (512 + tid) * 8;
  {
    int q = tid, r = q >> 3, p = q & 7, sp = p ^ (r & 7);
    a_off0 = (size_t)(row0 + r) * K + sp * 8;
    b_off0 = (size_t)(col0 + r) * K + sp * 8;
    q = 512 + tid; r = q >> 3; p = q & 7; sp = p ^ (r & 7);
    a_off1 = (size_t)(row0 + r) * K + sp * 8;
    b_off1 = (size_t)(col0 + r) * K + sp * 8;
  }

  f32x4 acc[4][2] = {};

  const int nkt = Kc >> 6;
  {
    int k0 = kbase;
    gload_lds16(&As[0][l_off0], A + a_off0 + k0);
    gload_lds16(&Bs[0][l_off0], W + b_off0 + k0);
    gload_lds16(&As[0][l_off1], A + a_off1 + k0);
    gload_lds16(&Bs[0][l_off1], W + b_off1 + k0);
  }
  __syncthreads();

  for (int kt = 0; kt < nkt; ++kt) {
    int cur = kt & 1;
    if (kt + 1 < nkt) {
      int k0 = kbase + ((kt + 1) << 6);
      gload_lds16(&As[cur ^ 1][l_off0], A + a_off0 + k0);
      gload_lds16(&Bs[cur ^ 1][l_off0], W + b_off0 + k0);
      gload_lds16(&As[cur ^ 1][l_off1], A + a_off1 + k0);
      gload_lds16(&Bs[cur ^ 1][l_off1], W + b_off1 + k0);
    }
#pragma unroll
    for (int kk = 0; kk < 2; ++kk) {
      short8 af[4], bfr[2];
#pragma unroll
      for (int m = 0; m < 4; ++m) {
        int r = wr * 64 + m * 16 + lr;
        int sc = (kk * 4 + lg) ^ (r & 7);
        af[m] = *(const short8*)(&As[cur][r * 64 + sc * 8]);
      }
#pragma unroll
      for (int n = 0; n < 2; ++n) {
        int r = wc * 32 + n * 16 + lr;
        int sc = (kk * 4 + lg) ^ (r & 7);
        bfr[n] = *(const short8*)(&Bs[cur][r * 64 + sc * 8]);
      }
#pragma unroll
      for (int m = 0; m < 4; ++m)
#pragma unroll
        for (int n = 0; n < 2; ++n)
          acc[m][n] = mfma16(af[m], bfr[n], acc[m][n]);
    }
    __syncthreads();
  }

#pragma unroll
  for (int n = 0; n < 2; ++n) {
    int cg = col0 + wc * 32 + n * 16 + lr;
    float bv = (EPI == EPI_ATOMIC) ? 0.f : bias[cg];
#pragma unroll
    for (int m = 0; m < 4; ++m) {
#pragma unroll
      for (int i = 0; i < 4; ++i) {
        int rg = row0 + wr * 64 + m * 16 + lg * 4 + i;
        float v = acc[m][n][i] + bv;
        if (EPI == EPI_BF16) {
          outb[(size_t)rg * N + cg] = f2bf(v);
        } else if (EPI == EPI_GELU) {
          outb[(size_t)rg * N + cg] = f2bf(gelu_tanh(v));
        } else if (EPI == EPI_RESID) {
          float r = res[(size_t)rg * N + cg];
          outf[(size_t)rg * N + cg] = r + gate[cg] * v;
        } else {
          atomicAdd(&outf[(size_t)rg * N + cg], gate[cg] * v);
        }
      }
    }
  }
}

// gemm3: 256x256 tile, BK=64, 512 threads (8 waves 2x4, per-wave 128x64),
// double-buffered 128 KiB LDS, counted-vmcnt pipeline (never drains to 0 in-loop).
// Per K-tile: stageA(t+1) | rdA kk0 | vmcnt(4) bar | rdB kk0 | 32 MFMA |
//             stageB(t+1) | rd kk1 | 32 MFMA | vmcnt(4) bar.
// vmcnt(4) #1 retires B(t) (A(t+1) stays in flight); #2 retires A(t+1).
template <int EPI>
__global__ __launch_bounds__(512, 2) void gemm3(const u16* __restrict__ A, const u16* __restrict__ W,
                                                const float* __restrict__ bias, u16* outb, float* outf,
                                                const float* __restrict__ gate,
                                                int M, int N, int K, int kchunks) {
  __shared__ u16 As[2][256 * 64];
  __shared__ u16 Bs[2][256 * 64];

  int nbx = gridDim.x;
  int nwg = gridDim.x * gridDim.y;
  int bid = blockIdx.y * gridDim.x + blockIdx.x;
  int cpx = nwg >> 3;
  int swz = (bid & 7) * cpx + (bid >> 3);
  int bx = swz % nbx, by = swz / nbx;
  int row0 = by * 256, col0 = bx * 256;
  const int Kc = K / kchunks;
  const int kbase = blockIdx.z * Kc;

  int tid = threadIdx.x;
  int lane = tid & 63, wid = tid >> 6;
  int wr = wid >> 2, wc = wid & 3;   // 2x4 waves, each owns 128x64
  int lr = lane & 15, lg = lane >> 4;

  // staging: 2048 16B chunks per matrix per tile; 4 chunks/thread each.
  u32 aoff[4], boff[4];
  int ldso[4];
#pragma unroll
  for (int j = 0; j < 4; ++j) {
    int q = tid + j * 512;
    int r = q >> 3, p = q & 7, sp = p ^ (r & 7);
    aoff[j] = (u32)(row0 + r) * (u32)K + sp * 8;
    boff[j] = (u32)(col0 + r) * (u32)K + sp * 8;
    ldso[j] = q * 8;
  }
  auto stageA = [&](int buf, int k0) {
#pragma unroll
    for (int j = 0; j < 4; ++j) gload_lds16(&As[buf][ldso[j]], A + aoff[j] + k0);
  };
  auto stageB = [&](int buf, int k0) {
#pragma unroll
    for (int j = 0; j < 4; ++j) gload_lds16(&Bs[buf][ldso[j]], W + boff[j] + k0);
  };
  const int scbase = lr & 7;
  auto rdA = [&](int buf, int kk, short8* af) {
    int sc = (kk * 4 + lg) ^ scbase;
#pragma unroll
    for (int m = 0; m < 8; ++m)
      af[m] = *(const short8*)(&As[buf][(wr * 128 + m * 16 + lr) * 64 + sc * 8]);
  };
  auto rdB = [&](int buf, int kk, short8* bf) {
    int sc = (kk * 4 + lg) ^ scbase;
#pragma unroll
    for (int n = 0; n < 4; ++n)
      bf[n] = *(const short8*)(&Bs[buf][(wc * 64 + n * 16 + lr) * 64 + sc * 8]);
  };

  f32x4 acc[8][4] = {};
  const int nkt = Kc >> 6;

  // prologue (one-time drain)
  stageA(0, kbase);
  stageB(0, kbase);
  VMCNT(0);
  SBAR();

  for (int kt = 0; kt < nkt - 1; ++kt) {
    int cur = kt & 1;
    int k1 = kbase + ((kt + 1) << 6);
    stageA(cur ^ 1, k1);                    // -> slot cur^1 (readers of its old tile passed last barrier)
    short8 af[8], bf[4];
    rdA(cur, 0, af);                        // A(kt) landed at previous boundary
    VMCNT(4);                               // retire B(kt); A(kt+1) stays in flight
    SBAR();                                 // all threads' B(kt) visible
    rdB(cur, 0, bf);
    __builtin_amdgcn_s_setprio(1);
#pragma unroll
    for (int m = 0; m < 8; ++m)
#pragma unroll
      for (int n = 0; n < 4; ++n)
        acc[m][n] = mfma16(af[m], bf[n], acc[m][n]);
    __builtin_amdgcn_s_setprio(0);
    stageB(cur ^ 1, k1);
    rdA(cur, 1, af);
    rdB(cur, 1, bf);
    __builtin_amdgcn_s_setprio(1);
#pragma unroll
    for (int m = 0; m < 8; ++m)
#pragma unroll
      for (int n = 0; n < 4; ++n)
        acc[m][n] = mfma16(af[m], bf[n], acc[m][n]);
    __builtin_amdgcn_s_setprio(0);
    VMCNT(4);                               // retire A(kt+1); B(kt+1) stays in flight
    SBAR();
  }
  {  // last tile (peeled): only B(last) may be outstanding
    int cur = (nkt - 1) & 1;
    short8 af[8], bf[4];
    rdA(cur, 0, af);
    VMCNT(0);
    SBAR();
    rdB(cur, 0, bf);
    __builtin_amdgcn_s_setprio(1);
#pragma unroll
    for (int m = 0; m < 8; ++m)
#pragma unroll
      for (int n = 0; n < 4; ++n)
        acc[m][n] = mfma16(af[m], bf[n], acc[m][n]);
    __builtin_amdgcn_s_setprio(0);
    rdA(cur, 1, af);
    rdB(cur, 1, bf);
    __builtin_amdgcn_s_setprio(1);
#pragma unroll
    for (int m = 0; m < 8; ++m)
#pragma unroll
      for (int n = 0; n < 4; ++n)
        acc[m][n] = mfma16(af[m], bf[n], acc[m][n]);
    __builtin_amdgcn_s_setprio(0);
  }

  // epilogue
#pragma unroll
  for (int n = 0; n < 4; ++n) {
    int cg = col0 + wc * 64 + n * 16 + lr;
    float bv = (EPI == EPI_ATOMIC) ? 0.f : bias[cg];
#pragma unroll
    for (int m = 0; m < 8; ++m) {
#pragma unroll
      for (int i = 0; i < 4; ++i) {
        int rg = row0 + wr * 128 + m * 16 + lg * 4 + i;
        float v = acc[m][n][i] + bv;
        if (EPI == EPI_BF16) {
          outb[(size_t)rg * N + cg] = f2bf(v);
        } else if (EPI == EPI_GELU) {
          outb[(size_t)rg * N + cg] = f2bf(gelu_tanh(v));
        } else {
          atomicAdd(&outf[(size_t)rg * N + cg], gate[cg] * v);
        }
      }
    }
  }
}

// ---------------- flash attention, swapped-QK^T 32x32 structure ----------------
template <int MASKED>
static __device__ __forceinline__ void attn_tile(const u16* Kt, const u16* Vp0, const u16* Vp1,
                                                 const short8* qf, int kb, int q0, int l31, int hi,
                                                 float& m, float& lsum, f32x16& o0, f32x16& o1) {
  f32x16 s0 = {}, s1 = {};
  const u16* kp0 = Kt + (size_t)l31 * 64 + hi * 8;
  const u16* kp1 = Kt + (size_t)(32 + l31) * 64 + hi * 8;
  __builtin_amdgcn_s_setprio(1);
#pragma unroll
  for (int s = 0; s < 4; ++s) {
    short8 kf0 = *(const short8*)(kp0 + s * 16);
    short8 kf1 = *(const short8*)(kp1 + s * 16);
    s0 = mfma32(kf0, qf[s], s0);   // S^T[k][q]
    s1 = mfma32(kf1, qf[s], s1);
  }
  __builtin_amdgcn_s_setprio(0);
  if (MASKED) {
    int qg = q0 + l31;
#pragma unroll
    for (int r = 0; r < 16; ++r) {
      int kk = kb + (r & 3) + 8 * (r >> 2) + 4 * hi;
      if (kk > qg) s0[r] = -INFINITY;
      if (kk + 32 > qg) s1[r] = -INFINITY;
    }
  }
  float pm = -INFINITY;
#pragma unroll
  for (int r = 0; r < 16; ++r) pm = fmaxf(pm, fmaxf(s0[r], s1[r]));
  pm = fmaxf(pm, __shfl_xor(pm, 32));
  if (!__all(pm <= m + DEFER_THR)) {
    float mn = fmaxf(m, pm);
    float al = exp2f(m - mn);
    m = mn;
    lsum *= al;
#pragma unroll
    for (int r = 0; r < 16; ++r) {
      float alr = __shfl(al, (r & 3) + 8 * (r >> 2) + 4 * hi);
      o0[r] *= alr;
      o1[r] *= alr;
    }
  }
  float ts = 0.f;
#pragma unroll
  for (int r = 0; r < 16; ++r) {
    float p0 = exp2f(s0[r] - m);
    float p1 = exp2f(s1[r] - m);
    s0[r] = p0; s1[r] = p1;
    ts += p0 + p1;
  }
  ts += __shfl_xor(ts, 32);
  lsum += ts;
  auto pack8 = [&](float a0, float a1, float a2, float a3,
                   float a4, float a5, float a6, float a7) -> short8 {
    u32 c0 = cvtpk_bf16(a0, a1), c1 = cvtpk_bf16(a2, a3);
    u32 c2 = cvtpk_bf16(a4, a5), c3 = cvtpk_bf16(a6, a7);
    u32x2 r02 = __builtin_amdgcn_permlane32_swap(c0, c2, false, false);
    u32x2 r13 = __builtin_amdgcn_permlane32_swap(c1, c3, false, false);
    u32x4 w;
    w[0] = r02[0]; w[1] = r13[0]; w[2] = r02[1]; w[3] = r13[1];
    return __builtin_bit_cast(short8, w);
  };
  short8 pa0 = pack8(s0[0], s0[1], s0[2], s0[3], s0[4], s0[5], s0[6], s0[7]);
  short8 pa1 = pack8(s0[8], s0[9], s0[10], s0[11], s0[12], s0[13], s0[14], s0[15]);
  short8 pa2 = pack8(s1[0], s1[1], s1[2], s1[3], s1[4], s1[5], s1[6], s1[7]);
  short8 pa3 = pack8(s1[8], s1[9], s1[10], s1[11], s1[12], s1[13], s1[14], s1[15]);
  short8 pa[4] = {pa0, pa1, pa2, pa3};
  __builtin_amdgcn_s_setprio(1);
#pragma unroll
  for (int ks = 0; ks < 4; ++ks) {
    short8 bv0 = *(const short8*)(Vp0 + ks * 16 + hi * 8);
    short8 bv1 = *(const short8*)(Vp1 + ks * 16 + hi * 8);
    o0 = mfma32(pa[ks], bv0, o0);
    o1 = mfma32(pa[ks], bv1, o1);
  }
  __builtin_amdgcn_s_setprio(0);
}

template <int CAUSAL>
__global__ __launch_bounds__(256) void flash_attn2(const u16* __restrict__ Q, const u16* __restrict__ K,
                                                   const u16* __restrict__ Vt, u16* __restrict__ O,
                                                   int Lq, int Lk) {
  const int wid = threadIdx.x >> 6, lane = threadIdx.x & 63;
  const int l31 = lane & 31, hi = lane >> 5;
  int wg = blockIdx.x * 4 + wid;     // 4 independent waves per block, no barriers
  int bh = wg & 63;
  int qc = wg >> 6;
  if (CAUSAL) qc = (Lq >> 5) - 1 - qc;   // heavy q-chunks dispatch first
  int q0 = qc << 5;

  const u16* Qb = Q + ((size_t)bh * Lq + q0) * 64;
  const u16* Kb = K + (size_t)bh * Lk * 64;
  const u16* Vb = Vt + (size_t)bh * 64 * Lk;

  short8 qf[4];
#pragma unroll
  for (int s = 0; s < 4; ++s) qf[s] = *(const short8*)(Qb + (size_t)l31 * 64 + s * 16 + hi * 8);

  f32x16 o0 = {}, o1 = {};
  float m = -INFINITY, lsum = 0.f;

  const u16* Kt = Kb;
  const u16* Vp0 = Vb + (size_t)l31 * Lk;
  const u16* Vp1 = Vb + (size_t)(32 + l31) * Lk;

  int nt = CAUSAL ? ((q0 >> 6) + 1) : (Lk >> 6);
  for (int t = 0; t < nt - 1; ++t) {
    attn_tile<0>(Kt, Vp0, Vp1, qf, t * 64, q0, l31, hi, m, lsum, o0, o1);
    Kt += 64 * 64; Vp0 += 64; Vp1 += 64;
  }
  if (CAUSAL)
    attn_tile<1>(Kt, Vp0, Vp1, qf, (nt - 1) * 64, q0, l31, hi, m, lsum, o0, o1);
  else
    attn_tile<0>(Kt, Vp0, Vp1, qf, (nt - 1) * 64, q0, l31, hi, m, lsum, o0, o1);

  float myinv = 1.f / lsum;
  int b = bh >> 4, h = bh & 15;
#pragma unroll
  for (int r = 0; r < 16; ++r) {
    int cr = (r & 3) + 8 * (r >> 2) + 4 * hi;
    float li = __shfl(myinv, cr);
    u16* op = O + ((size_t)b * Lq + q0 + cr) * 1024 + h * 64;
    op[l31] = f2bf(o0[r] * li);
    op[32 + l31] = f2bf(o1[r] * li);
  }
}

// ---------------- launch ----------------
extern "C" void kernel_launch(void* const* d_in, const int* in_sizes, int n_in,
                              void* d_out, int out_size, void* d_ws, size_t ws_size,
                              hipStream_t stream) {
  (void)in_sizes; (void)n_in; (void)out_size;
  if (ws_size < WS_NEED) return;  // need ~105 MB scratch

  const float* x     = (const float*)d_in[0];
  const float* ctx   = (const float*)d_in[1];
  const float* g_msa = (const float*)d_in[3];
  const float* g_ca  = (const float*)d_in[4];
  const float* g_mlp = (const float*)d_in[5];
  const float* n1w = (const float*)d_in[6],  *n1b = (const float*)d_in[7];
  const float* n2w = (const float*)d_in[8],  *n2b = (const float*)d_in[9];
  const float* n3w = (const float*)d_in[10], *n3b = (const float*)d_in[11];
  const float* sa_qw = (const float*)d_in[12], *sa_kw = (const float*)d_in[14];
  const float* sa_vw = (const float*)d_in[16], *sa_pw = (const float*)d_in[18];
  const float* sa_qb = (const float*)d_in[13], *sa_kb = (const float*)d_in[15];
  const float* sa_vb = (const float*)d_in[17], *sa_pb = (const float*)d_in[19];
  const float* ca_qw = (const float*)d_in[20], *ca_qb = (const float*)d_in[21];
  const float* ca_kw = (const float*)d_in[22], *ca_kb = (const float*)d_in[23];
  const float* ca_vw = (const float*)d_in[24], *ca_vb = (const float*)d_in[25];
  const float* ca_pw = (const float*)d_in[26], *ca_pb = (const float*)d_in[27];
  const float* fc1w = (const float*)d_in[28], *fc1b = (const float*)d_in[29];
  const float* fc2w = (const float*)d_in[30], *fc2b = (const float*)d_in[31];

  char* ws = (char*)d_ws;
  float* out = (float*)d_out;
  float* tcos = (float*)(ws + OFF_TCOS);
  float* tsin = (float*)(ws + OFF_TSIN);
  u16* Hb   = (u16*)(ws + OFF_H);
  u16* QKV  = (u16*)(ws + OFF_QKV);
  u16* QR   = (u16*)(ws + OFF_QR);
  u16* KR   = (u16*)(ws + OFF_KR);
  u16* VT   = (u16*)(ws + OFF_VT);
  u16* AO   = (u16*)(ws + OFF_AO);

  // RoPE tables
  build_tab<<<dim3(128), dim3(256), 0, stream>>>(tcos, tsin);

  // fused weight/context conversion (fp32 -> bf16) into contiguous ws region
  Cvt11 ca;
  ca.s[0] = sa_qw; ca.s[1] = sa_kw; ca.s[2] = sa_vw; ca.s[3] = sa_pw;
  ca.s[4] = ca_qw; ca.s[5] = ca_kw; ca.s[6] = ca_vw; ca.s[7] = ca_pw;
  ca.s[8] = fc1w;  ca.s[9] = fc2w;  ca.s[10] = ctx;
  cvt_all<<<dim3(18432), dim3(256), 0, stream>>>(ca, (u16*)(ws + OFF_WSAQKV));
  Cp5 cp;
  cp.s[0] = sa_qb; cp.s[1] = sa_kb; cp.s[2] = sa_vb; cp.s[3] = ca_kb; cp.s[4] = ca_vb;
  copy5<<<dim3(20), dim3(256), 0, stream>>>(cp, (float*)(ws + OFF_BSAQKV));

  // ---- self-attention ----
  ln_bf16<<<dim3(NTOK), dim3(256), 0, stream>>>(x, n1w, n1b, Hb);
  gemm3<EPI_BF16><<<dim3(3072 / 256, NTOK / 256), dim3(512), 0, stream>>>(
      Hb, (u16*)(ws + OFF_WSAQKV), (float*)(ws + OFF_BSAQKV), QKV, nullptr, nullptr,
      NTOK, 3072, 1024, 1);
  rope_scatter<1, 0><<<dim3(NTOK), dim3(128), 0, stream>>>(QKV, 3072, 0, QR, tcos, tsin, LQ, QSCALE);
  rope_scatter<1, 0><<<dim3(NTOK), dim3(128), 0, stream>>>(QKV, 3072, 1024, KR, tcos, tsin, LQ, 1.0f);
  rope_scatter<0, 1><<<dim3(NTOK), dim3(128), 0, stream>>>(QKV, 3072, 2048, VT, tcos, tsin, LQ, 1.0f);
  flash_attn2<1><<<dim3(512), dim3(256), 0, stream>>>(QR, KR, VT, AO, LQ, LQ);
  gemm2<EPI_RESID><<<dim3(1024 / 128, NTOK / 128), dim3(512), 0, stream>>>(
      AO, (u16*)(ws + OFF_WSAP), sa_pb, nullptr, out, x, g_msa, NTOK, 1024, 1024, 1);

  // ---- cross-attention ----
  ln_bf16<<<dim3(NTOK), dim3(256), 0, stream>>>(out, n2w, n2b, Hb);
  gemm2<EPI_BF16><<<dim3(1024 / 128, NTOK / 128), dim3(512), 0, stream>>>(
      Hb, (u16*)(ws + OFF_WCAQ), ca_qb, (u16*)(ws + OFF_CAQ), nullptr, nullptr, nullptr,
      NTOK, 1024, 1024, 1);
  gemm2<EPI_BF16><<<dim3(2048 / 128, NCTX / 128), dim3(512), 0, stream>>>(
      (u16*)(ws + OFF_CTXB), (u16*)(ws + OFF_WCAKV), (float*)(ws + OFF_BCAKV),
      (u16*)(ws + OFF_CAKV), nullptr, nullptr, nullptr, NCTX, 2048, 1024, 1);
  rope_scatter<1, 0><<<dim3(NTOK), dim3(128), 0, stream>>>((u16*)(ws + OFF_CAQ), 1024, 0, QR, tcos, tsin, LQ, QSCALE);
  rope_scatter<1, 0><<<dim3(NCTX), dim3(128), 0, stream>>>((u16*)(ws + OFF_CAKV), 2048, 0, KR, tcos, tsin, LC, 1.0f);
  rope_scatter<0, 1><<<dim3(NCTX), dim3(128), 0, stream>>>((u16*)(ws + OFF_CAKV), 2048, 1024, VT, tcos, tsin, LC, 1.0f);
  flash_attn2<0><<<dim3(512), dim3(256), 0, stream>>>(QR, KR, VT, AO, LQ, LC);
  gemm2<EPI_RESID><<<dim3(1024 / 128, NTOK / 128), dim3(512), 0, stream>>>(
      AO, (u16*)(ws + OFF_WCAP), ca_pb, nullptr, out, out, g_ca, NTOK, 1024, 1024, 1);

  // ---- MLP ----
  ln_bf16<<<dim3(NTOK), dim3(256), 0, stream>>>(out, n3w, n3b, Hb);
  gemm3<EPI_GELU><<<dim3(4096 / 256, NTOK / 256), dim3(512), 0, stream>>>(
      Hb, (u16*)(ws + OFF_WFC1), fc1b, (u16*)(ws + OFF_U), nullptr, nullptr,
      NTOK, 4096, 1024, 1);
  // fc2: split-K x4, atomic accumulation; bias+gate pre-applied
  init_bias_gate<<<dim3(4096), dim3(256), 0, stream>>>(out, fc2b, g_mlp);
  gemm3<EPI_ATOMIC><<<dim3(1024 / 256, NTOK / 256, 4), dim3(512), 0, stream>>>(
      (u16*)(ws + OFF_U), (u16*)(ws + OFF_WFC2), nullptr, nullptr, out, g_mlp,
      NTOK, 1024, 4096, 4);
}

// Round 5
// 441.740 us; speedup vs baseline: 1.0377x; 1.0377x over previous
//
#include <hip/hip_runtime.h>
#include <math.h>

typedef __attribute__((ext_vector_type(8))) short short8;
typedef __attribute__((ext_vector_type(4))) float f32x4;
typedef __attribute__((ext_vector_type(16))) float f32x16;
typedef unsigned short u16;
typedef unsigned int u32;
typedef __attribute__((ext_vector_type(2))) u32 u32x2;
typedef __attribute__((ext_vector_type(4))) u32 u32x4;
typedef unsigned long long u64;

static constexpr int E = 1024, H = 16, LQ = 1024, LC = 512, Bn = 4, FF = 4096;
static constexpr int NTOK = Bn * LQ;   // 4096
static constexpr int NCTX = Bn * LC;   // 2048

// Q pre-scale: 1/sqrt(64) * log2(e)  (softmax runs in exp2 domain)
#define QSCALE 0.1803368801111244f
#define DEFER_THR 11.5f

// ---------------- workspace layout (bytes) ----------------
static constexpr size_t OFF_TCOS   = 0;                                    // 1024*32 f32
static constexpr size_t OFF_TSIN   = OFF_TCOS + (size_t)LQ*32*4;
static constexpr size_t OFF_BSAQKV = OFF_TSIN + (size_t)LQ*32*4;           // 3072 f32 (+ca_k/v bias after)
static constexpr size_t OFF_BCAKV  = OFF_BSAQKV + 16384;                   // 2048 f32
// contiguous bf16 weight region (order matters for cvt_all):
static constexpr size_t OFF_WSAQKV = OFF_BCAKV + 16384;                    // [3072][1024] bf16
static constexpr size_t OFF_WSAP   = OFF_WSAQKV + (size_t)3072*1024*2;     // [1024][1024]
static constexpr size_t OFF_WCAQ   = OFF_WSAP   + (size_t)1024*1024*2;
static constexpr size_t OFF_WCAKV  = OFF_WCAQ   + (size_t)1024*1024*2;     // [2048][1024]
static constexpr size_t OFF_WCAP   = OFF_WCAKV  + (size_t)2048*1024*2;
static constexpr size_t OFF_WFC1   = OFF_WCAP   + (size_t)1024*1024*2;     // [4096][1024]
static constexpr size_t OFF_WFC2   = OFF_WFC1   + (size_t)4096*1024*2;     // [1024][4096]
static constexpr size_t OFF_CTXB   = OFF_WFC2   + (size_t)1024*4096*2;     // [2048][1024] bf16
static constexpr size_t OFF_H      = OFF_CTXB   + (size_t)2048*1024*2;     // [4096][1024] bf16 (LN out)
static constexpr size_t OFF_QKV    = OFF_H      + (size_t)4096*1024*2;     // [4096][3072] bf16
static constexpr size_t OFF_CAQ    = OFF_QKV;                              // [4096][1024]
static constexpr size_t OFF_CAKV   = OFF_QKV + (size_t)4096*1024*2;        // [2048][2048]
static constexpr size_t OFF_QR     = OFF_QKV + (size_t)4096*3072*2;        // [B,H,LQ,64]
static constexpr size_t OFF_KR     = OFF_QR  + (size_t)4096*1024*2;        // [B,H,Lk,64]
static constexpr size_t OFF_VT     = OFF_KR  + (size_t)4096*1024*2;        // [B,H,64,Lk]
static constexpr size_t OFF_AO     = OFF_VT  + (size_t)4096*1024*2;        // [4096][1024] bf16
static constexpr size_t OFF_U      = OFF_QKV;                              // fc1 out [4096][4096] bf16 reuses QKV+QR
static constexpr size_t WS_NEED    = OFF_AO + (size_t)4096*1024*2;         // ~105 MB

// ---------------- helpers ----------------
static __device__ __forceinline__ float bf2f(u16 u) {
  union { u32 i; float f; } un; un.i = ((u32)u) << 16; return un.f;
}
static __device__ __forceinline__ u16 f2bf(float f) {  // RNE
  union { float f; u32 u; } un; un.f = f;
  u32 u = un.u;
  return (u16)((u + 0x7FFFu + ((u >> 16) & 1u)) >> 16);
}
static __device__ __forceinline__ u64 pack4(u16 a, u16 b, u16 c, u16 d) {
  return (u64)a | ((u64)b << 16) | ((u64)c << 32) | ((u64)d << 48);
}
static __device__ __forceinline__ f32x4 mfma16(short8 a, short8 b, f32x4 c) {
  return __builtin_amdgcn_mfma_f32_16x16x32_bf16(a, b, c, 0, 0, 0);
}
static __device__ __forceinline__ f32x16 mfma32(short8 a, short8 b, f32x16 c) {
  return __builtin_amdgcn_mfma_f32_32x32x16_bf16(a, b, c, 0, 0, 0);
}
static __device__ __forceinline__ void gload_lds16(void* lds, const void* g) {
  __builtin_amdgcn_global_load_lds(
      (const __attribute__((address_space(1))) void*)g,
      (__attribute__((address_space(3))) void*)lds, 16, 0, 0);
}
static __device__ __forceinline__ float gelu_tanh(float x) {
  float t = tanhf(0.7978845608028654f * (x + 0.044715f * x * x * x));
  return 0.5f * x * (1.0f + t);
}
static __device__ __forceinline__ u32 cvtpk_bf16(float lo, float hi) {
  u32 r;
  asm("v_cvt_pk_bf16_f32 %0, %1, %2" : "=v"(r) : "v"(lo), "v"(hi));
  return r;
}

// ---------------- small kernels ----------------
__global__ __launch_bounds__(256) void build_tab(float* __restrict__ ct, float* __restrict__ st) {
  int idx = blockIdx.x * 256 + threadIdx.x;           // 1024*32 entries
  int pos = idx >> 5, i = idx & 31;
  float inv = powf(10000.f, -(float)i * (1.f / 32.f));
  float a = (float)pos * inv;
  ct[idx] = cosf(a);
  st[idx] = sinf(a);
}

// fused fp32->bf16 conversion of all weights + context into the contiguous
// bf16 ws region. 11 segments, sizes (in 4-elem units): 8 x 262144, 2 x 1048576, 524288.
struct Cvt11 { const float* s[11]; };
__global__ __launch_bounds__(256) void cvt_all(Cvt11 a, u16* __restrict__ dst) {
  u32 gid = blockIdx.x * 256 + threadIdx.x;   // 0 .. 4718591
  u32 s, off;
  if (gid < 2097152u)      { s = gid >> 18;                        off = gid & 262143u; }
  else if (gid < 4194304u) { u32 t = gid - 2097152u; s = 8 + (t >> 20); off = t & 1048575u; }
  else                     { s = 10;                               off = gid - 4194304u; }
  float4 v = *(const float4*)(a.s[s] + (size_t)off * 4);
  *(u64*)(dst + (size_t)gid * 4) = pack4(f2bf(v.x), f2bf(v.y), f2bf(v.z), f2bf(v.w));
}

// fused bias copies: sa_q,sa_k,sa_v -> BSAQKV(+0,+1024,+2048); ca_k,ca_v -> BCAKV(+0,+1024)
struct Cp5 { const float* s[5]; };
__global__ __launch_bounds__(256) void copy5(Cp5 a, float* __restrict__ dst) {
  int gid = blockIdx.x * 256 + threadIdx.x;   // 0..5119
  int s = gid >> 10, off = gid & 1023;
  int doff = (s < 3) ? s * 1024 : 4096 + (s - 3) * 1024;
  dst[doff + off] = a.s[s][off];
}

// out[row][c] += gate[c]*bias[c]  (init pass for split-K atomic GEMM)
__global__ __launch_bounds__(256) void init_bias_gate(float* __restrict__ out, const float* __restrict__ bias,
                                                      const float* __restrict__ gate) {
  int i = (blockIdx.x * 256 + threadIdx.x) * 4;
  int c = i & 1023;
  float4 o = *(float4*)(out + i);
  o.x += gate[c] * bias[c];
  o.y += gate[c + 1] * bias[c + 1];
  o.z += gate[c + 2] * bias[c + 2];
  o.w += gate[c + 3] * bias[c + 3];
  *(float4*)(out + i) = o;
}

// LN over last dim 1024, one row per block (256 threads, 4 f32 each), bf16 out.
__global__ __launch_bounds__(256) void ln_bf16(const float* __restrict__ x, const float* __restrict__ w,
                                               const float* __restrict__ b, u16* __restrict__ out) {
  __shared__ float red[4];
  int row = blockIdx.x, tid = threadIdx.x;
  const float* xr = x + (size_t)row * 1024;
  float4 v = ((const float4*)xr)[tid];
  float s = v.x + v.y + v.z + v.w;
#pragma unroll
  for (int off = 32; off; off >>= 1) s += __shfl_xor(s, off);
  if ((tid & 63) == 0) red[tid >> 6] = s;
  __syncthreads();
  float mean = (red[0] + red[1] + red[2] + red[3]) * (1.f / 1024.f);
  float dx = v.x - mean, dy = v.y - mean, dz = v.z - mean, dw = v.w - mean;
  float sq = dx * dx + dy * dy + dz * dz + dw * dw;
#pragma unroll
  for (int off = 32; off; off >>= 1) sq += __shfl_xor(sq, off);
  __syncthreads();
  if ((tid & 63) == 0) red[tid >> 6] = sq;
  __syncthreads();
  float var = (red[0] + red[1] + red[2] + red[3]) * (1.f / 1024.f);
  float rstd = rsqrtf(var + 1e-6f);
  float4 wv = ((const float4*)w)[tid];
  float4 bv = ((const float4*)b)[tid];
  u64 o = pack4(f2bf(dx * rstd * wv.x + bv.x), f2bf(dy * rstd * wv.y + bv.y),
                f2bf(dz * rstd * wv.z + bv.z), f2bf(dw * rstd * wv.w + bv.w));
  *(u64*)(out + (size_t)row * 1024 + tid * 4) = o;
}

// RoPE + layout scatter. src [T][ld] bf16 (+col0), 128 threads x 8 elems per token.
template <int ROPE, int TRANS>
__global__ __launch_bounds__(128) void rope_scatter(const u16* __restrict__ src, int ld, int col0,
                                                    u16* __restrict__ dst,
                                                    const float* __restrict__ cosT,
                                                    const float* __restrict__ sinT, int Lper,
                                                    float scale) {
  int t = blockIdx.x;
  int b = t / Lper, l = t - b * Lper;
  int tid = threadIdx.x;
  int e0 = tid * 8;
  int h = e0 >> 6, d0 = e0 & 63;
  short8 vv = *(const short8*)(src + (size_t)t * ld + col0 + e0);
  if (ROPE) {
    short8 ov;
#pragma unroll
    for (int j = 0; j < 4; ++j) {
      float x1 = bf2f((u16)vv[2 * j]);
      float x2 = bf2f((u16)vv[2 * j + 1]);
      int i = (d0 >> 1) + j;
      float c = cosT[l * 32 + i], s = sinT[l * 32 + i];
      ov[2 * j]     = (short)f2bf((x1 * c - x2 * s) * scale);
      ov[2 * j + 1] = (short)f2bf((x1 * s + x2 * c) * scale);
    }
    *(short8*)(dst + (((size_t)b * H + h) * Lper + l) * 64 + d0) = ov;
  } else if (TRANS) {
#pragma unroll
    for (int m = 0; m < 8; ++m)
      dst[(((size_t)b * H + h) * 64 + d0 + m) * Lper + l] = (u16)vv[m];
  }
}

// ---------------- GEMM kernels: C[M,N] = A[M,K] @ W[N,K]^T + bias ----------------
enum { EPI_BF16 = 0, EPI_GELU = 1, EPI_RESID = 2, EPI_ATOMIC = 3 };

// gemm2: 128x128 tile, 512 threads, 2-phase dbuf (proven). For N<=2048 GEMMs.
template <int EPI>
__global__ __launch_bounds__(512, 4) void gemm2(const u16* __restrict__ A, const u16* __restrict__ W,
                                                const float* __restrict__ bias, u16* outb, float* outf,
                                                const float* res, const float* __restrict__ gate,
                                                int M, int N, int K, int kchunks) {
  __shared__ u16 As[2][128 * 64];
  __shared__ u16 Bs[2][128 * 64];

  int nwg = gridDim.x * gridDim.y;
  int bid = blockIdx.y * gridDim.x + blockIdx.x;
  int cpx = nwg >> 3;
  int swz = (bid & 7) * cpx + (bid >> 3);
  int bx = swz % gridDim.x;
  int by = swz / gridDim.x;
  int row0 = by * 128, col0 = bx * 128;

  const int Kc = K / kchunks;
  const int kbase = blockIdx.z * Kc;

  int tid = threadIdx.x;
  int lane = tid & 63, wid = tid >> 6;
  int wr = wid >> 2, wc = wid & 3;  // 2x4 waves, each owns 64x32
  int lr = lane & 15, lg = lane >> 4;

  size_t a_off0, a_off1, b_off0, b_off1;
  int l_off0 = tid * 8, l_off1 = (512 + tid) * 8;
  {
    int q = tid, r = q >> 3, p = q & 7, sp = p ^ (r & 7);
    a_off0 = (size_t)(row0 + r) * K + sp * 8;
    b_off0 = (size_t)(col0 + r) * K + sp * 8;
    q = 512 + tid; r = q >> 3; p = q & 7; sp = p ^ (r & 7);
    a_off1 = (size_t)(row0 + r) * K + sp * 8;
    b_off1 = (size_t)(col0 + r) * K + sp * 8;
  }

  f32x4 acc[4][2] = {};

  const int nkt = Kc >> 6;
  {
    int k0 = kbase;
    gload_lds16(&As[0][l_off0], A + a_off0 + k0);
    gload_lds16(&Bs[0][l_off0], W + b_off0 + k0);
    gload_lds16(&As[0][l_off1], A + a_off1 + k0);
    gload_lds16(&Bs[0][l_off1], W + b_off1 + k0);
  }
  __syncthreads();

  for (int kt = 0; kt < nkt; ++kt) {
    int cur = kt & 1;
    if (kt + 1 < nkt) {
      int k0 = kbase + ((kt + 1) << 6);
      gload_lds16(&As[cur ^ 1][l_off0], A + a_off0 + k0);
      gload_lds16(&Bs[cur ^ 1][l_off0], W + b_off0 + k0);
      gload_lds16(&As[cur ^ 1][l_off1], A + a_off1 + k0);
      gload_lds16(&Bs[cur ^ 1][l_off1], W + b_off1 + k0);
    }
#pragma unroll
    for (int kk = 0; kk < 2; ++kk) {
      short8 af[4], bfr[2];
#pragma unroll
      for (int m = 0; m < 4; ++m) {
        int r = wr * 64 + m * 16 + lr;
        int sc = (kk * 4 + lg) ^ (r & 7);
        af[m] = *(const short8*)(&As[cur][r * 64 + sc * 8]);
      }
#pragma unroll
      for (int n = 0; n < 2; ++n) {
        int r = wc * 32 + n * 16 + lr;
        int sc = (kk * 4 + lg) ^ (r & 7);
        bfr[n] = *(const short8*)(&Bs[cur][r * 64 + sc * 8]);
      }
#pragma unroll
      for (int m = 0; m < 4; ++m)
#pragma unroll
        for (int n = 0; n < 2; ++n)
          acc[m][n] = mfma16(af[m], bfr[n], acc[m][n]);
    }
    __syncthreads();
  }

#pragma unroll
  for (int n = 0; n < 2; ++n) {
    int cg = col0 + wc * 32 + n * 16 + lr;
    float bv = (EPI == EPI_ATOMIC) ? 0.f : bias[cg];
#pragma unroll
    for (int m = 0; m < 4; ++m) {
#pragma unroll
      for (int i = 0; i < 4; ++i) {
        int rg = row0 + wr * 64 + m * 16 + lg * 4 + i;
        float v = acc[m][n][i] + bv;
        if (EPI == EPI_BF16) {
          outb[(size_t)rg * N + cg] = f2bf(v);
        } else if (EPI == EPI_GELU) {
          outb[(size_t)rg * N + cg] = f2bf(gelu_tanh(v));
        } else if (EPI == EPI_RESID) {
          float r = res[(size_t)rg * N + cg];
          outf[(size_t)rg * N + cg] = r + gate[cg] * v;
        } else {
          atomicAdd(&outf[(size_t)rg * N + cg], gate[cg] * v);
        }
      }
    }
  }
}

// gemm3: 256x256 tile, BK=64, 512 threads (8 waves 2x4, per-wave 128x64),
// double-buffered 128 KiB LDS. Single-drain 2-phase schedule (m105/m248-class):
//   stageA(t+1) | rd kk0 | 32 MFMA | stageB(t+1) | rd kk1 | 32 MFMA | syncthreads.
// Issue-to-wait distance for staged loads = ~full K-iteration (24 ds_read + 64
// MFMA), so L2/HBM latency is covered; hazard structure identical to gemm2.
template <int EPI>
__global__ __launch_bounds__(512, 2) void gemm3(const u16* __restrict__ A, const u16* __restrict__ W,
                                                const float* __restrict__ bias, u16* outb, float* outf,
                                                const float* __restrict__ gate,
                                                int M, int N, int K, int kchunks) {
  __shared__ u16 As[2][256 * 64];
  __shared__ u16 Bs[2][256 * 64];

  int nbx = gridDim.x;
  int nwg = gridDim.x * gridDim.y;
  int bid = blockIdx.y * gridDim.x + blockIdx.x;
  int cpx = nwg >> 3;
  int swz = (bid & 7) * cpx + (bid >> 3);
  int bx = swz % nbx, by = swz / nbx;
  int row0 = by * 256, col0 = bx * 256;
  const int Kc = K / kchunks;
  const int kbase = blockIdx.z * Kc;

  int tid = threadIdx.x;
  int lane = tid & 63, wid = tid >> 6;
  int wr = wid >> 2, wc = wid & 3;   // 2x4 waves, each owns 128x64
  int lr = lane & 15, lg = lane >> 4;

  // staging: 2048 16B chunks per matrix per tile; 4 chunks/thread each.
  u32 aoff[4], boff[4];
  int ldso[4];
#pragma unroll
  for (int j = 0; j < 4; ++j) {
    int q = tid + j * 512;
    int r = q >> 3, p = q & 7, sp = p ^ (r & 7);
    aoff[j] = (u32)(row0 + r) * (u32)K + sp * 8;
    boff[j] = (u32)(col0 + r) * (u32)K + sp * 8;
    ldso[j] = q * 8;
  }
  auto stageA = [&](int buf, int k0) {
#pragma unroll
    for (int j = 0; j < 4; ++j) gload_lds16(&As[buf][ldso[j]], A + aoff[j] + k0);
  };
  auto stageB = [&](int buf, int k0) {
#pragma unroll
    for (int j = 0; j < 4; ++j) gload_lds16(&Bs[buf][ldso[j]], W + boff[j] + k0);
  };
  const int scbase = lr & 7;
  auto rdA = [&](int buf, int kk, short8* af) {
    int sc = (kk * 4 + lg) ^ scbase;
#pragma unroll
    for (int m = 0; m < 8; ++m)
      af[m] = *(const short8*)(&As[buf][(wr * 128 + m * 16 + lr) * 64 + sc * 8]);
  };
  auto rdB = [&](int buf, int kk, short8* bf) {
    int sc = (kk * 4 + lg) ^ scbase;
#pragma unroll
    for (int n = 0; n < 4; ++n)
      bf[n] = *(const short8*)(&Bs[buf][(wc * 64 + n * 16 + lr) * 64 + sc * 8]);
  };

  f32x4 acc[8][4] = {};
  const int nkt = Kc >> 6;

  // prologue
  stageA(0, kbase);
  stageB(0, kbase);
  __syncthreads();

  for (int kt = 0; kt < nkt; ++kt) {
    int cur = kt & 1;
    int k1 = kbase + ((kt + 1) << 6);
    short8 af[8], bf[4];
    if (kt + 1 < nkt) stageA(cur ^ 1, k1);   // writes buffer whose readers passed last barrier
    rdA(cur, 0, af);
    rdB(cur, 0, bf);
    __builtin_amdgcn_s_setprio(1);
#pragma unroll
    for (int m = 0; m < 8; ++m)
#pragma unroll
      for (int n = 0; n < 4; ++n)
        acc[m][n] = mfma16(af[m], bf[n], acc[m][n]);
    __builtin_amdgcn_s_setprio(0);
    if (kt + 1 < nkt) stageB(cur ^ 1, k1);
    rdA(cur, 1, af);
    rdB(cur, 1, bf);
    __builtin_amdgcn_s_setprio(1);
#pragma unroll
    for (int m = 0; m < 8; ++m)
#pragma unroll
      for (int n = 0; n < 4; ++n)
        acc[m][n] = mfma16(af[m], bf[n], acc[m][n]);
    __builtin_amdgcn_s_setprio(0);
    __syncthreads();   // vmcnt(0)+lgkmcnt(0)+barrier: tile t+1 landed, buffers swappable
  }

  // epilogue
#pragma unroll
  for (int n = 0; n < 4; ++n) {
    int cg = col0 + wc * 64 + n * 16 + lr;
    float bv = (EPI == EPI_ATOMIC) ? 0.f : bias[cg];
#pragma unroll
    for (int m = 0; m < 8; ++m) {
#pragma unroll
      for (int i = 0; i < 4; ++i) {
        int rg = row0 + wr * 128 + m * 16 + lg * 4 + i;
        float v = acc[m][n][i] + bv;
        if (EPI == EPI_BF16) {
          outb[(size_t)rg * N + cg] = f2bf(v);
        } else if (EPI == EPI_GELU) {
          outb[(size_t)rg * N + cg] = f2bf(gelu_tanh(v));
        } else {
          atomicAdd(&outf[(size_t)rg * N + cg], gate[cg] * v);
        }
      }
    }
  }
}

// ---------------- flash attention, swapped-QK^T 32x32 structure ----------------
template <int MASKED>
static __device__ __forceinline__ void attn_tile(const u16* Kt, const u16* Vp0, const u16* Vp1,
                                                 const short8* qf, int kb, int q0, int l31, int hi,
                                                 float& m, float& lsum, f32x16& o0, f32x16& o1) {
  f32x16 s0 = {}, s1 = {};
  const u16* kp0 = Kt + (size_t)l31 * 64 + hi * 8;
  const u16* kp1 = Kt + (size_t)(32 + l31) * 64 + hi * 8;
  __builtin_amdgcn_s_setprio(1);
#pragma unroll
  for (int s = 0; s < 4; ++s) {
    short8 kf0 = *(const short8*)(kp0 + s * 16);
    short8 kf1 = *(const short8*)(kp1 + s * 16);
    s0 = mfma32(kf0, qf[s], s0);   // S^T[k][q]
    s1 = mfma32(kf1, qf[s], s1);
  }
  __builtin_amdgcn_s_setprio(0);
  if (MASKED) {
    int qg = q0 + l31;
#pragma unroll
    for (int r = 0; r < 16; ++r) {
      int kk = kb + (r & 3) + 8 * (r >> 2) + 4 * hi;
      if (kk > qg) s0[r] = -INFINITY;
      if (kk + 32 > qg) s1[r] = -INFINITY;
    }
  }
  float pm = -INFINITY;
#pragma unroll
  for (int r = 0; r < 16; ++r) pm = fmaxf(pm, fmaxf(s0[r], s1[r]));
  pm = fmaxf(pm, __shfl_xor(pm, 32));
  if (!__all(pm <= m + DEFER_THR)) {
    float mn = fmaxf(m, pm);
    float al = exp2f(m - mn);
    m = mn;
    lsum *= al;
#pragma unroll
    for (int r = 0; r < 16; ++r) {
      float alr = __shfl(al, (r & 3) + 8 * (r >> 2) + 4 * hi);
      o0[r] *= alr;
      o1[r] *= alr;
    }
  }
  float ts = 0.f;
#pragma unroll
  for (int r = 0; r < 16; ++r) {
    float p0 = exp2f(s0[r] - m);
    float p1 = exp2f(s1[r] - m);
    s0[r] = p0; s1[r] = p1;
    ts += p0 + p1;
  }
  ts += __shfl_xor(ts, 32);
  lsum += ts;
  auto pack8 = [&](float a0, float a1, float a2, float a3,
                   float a4, float a5, float a6, float a7) -> short8 {
    u32 c0 = cvtpk_bf16(a0, a1), c1 = cvtpk_bf16(a2, a3);
    u32 c2 = cvtpk_bf16(a4, a5), c3 = cvtpk_bf16(a6, a7);
    u32x2 r02 = __builtin_amdgcn_permlane32_swap(c0, c2, false, false);
    u32x2 r13 = __builtin_amdgcn_permlane32_swap(c1, c3, false, false);
    u32x4 w;
    w[0] = r02[0]; w[1] = r13[0]; w[2] = r02[1]; w[3] = r13[1];
    return __builtin_bit_cast(short8, w);
  };
  short8 pa0 = pack8(s0[0], s0[1], s0[2], s0[3], s0[4], s0[5], s0[6], s0[7]);
  short8 pa1 = pack8(s0[8], s0[9], s0[10], s0[11], s0[12], s0[13], s0[14], s0[15]);
  short8 pa2 = pack8(s1[0], s1[1], s1[2], s1[3], s1[4], s1[5], s1[6], s1[7]);
  short8 pa3 = pack8(s1[8], s1[9], s1[10], s1[11], s1[12], s1[13], s1[14], s1[15]);
  short8 pa[4] = {pa0, pa1, pa2, pa3};
  __builtin_amdgcn_s_setprio(1);
#pragma unroll
  for (int ks = 0; ks < 4; ++ks) {
    short8 bv0 = *(const short8*)(Vp0 + ks * 16 + hi * 8);
    short8 bv1 = *(const short8*)(Vp1 + ks * 16 + hi * 8);
    o0 = mfma32(pa[ks], bv0, o0);
    o1 = mfma32(pa[ks], bv1, o1);
  }
  __builtin_amdgcn_s_setprio(0);
}

template <int CAUSAL>
__global__ __launch_bounds__(256) void flash_attn2(const u16* __restrict__ Q, const u16* __restrict__ K,
                                                   const u16* __restrict__ Vt, u16* __restrict__ O,
                                                   int Lq, int Lk) {
  const int wid = threadIdx.x >> 6, lane = threadIdx.x & 63;
  const int l31 = lane & 31, hi = lane >> 5;
  int wg = blockIdx.x * 4 + wid;     // 4 independent waves per block, no barriers
  int bh = wg & 63;
  int qc = wg >> 6;
  if (CAUSAL) qc = (Lq >> 5) - 1 - qc;   // heavy q-chunks dispatch first
  int q0 = qc << 5;

  const u16* Qb = Q + ((size_t)bh * Lq + q0) * 64;
  const u16* Kb = K + (size_t)bh * Lk * 64;
  const u16* Vb = Vt + (size_t)bh * 64 * Lk;

  short8 qf[4];
#pragma unroll
  for (int s = 0; s < 4; ++s) qf[s] = *(const short8*)(Qb + (size_t)l31 * 64 + s * 16 + hi * 8);

  f32x16 o0 = {}, o1 = {};
  float m = -INFINITY, lsum = 0.f;

  const u16* Kt = Kb;
  const u16* Vp0 = Vb + (size_t)l31 * Lk;
  const u16* Vp1 = Vb + (size_t)(32 + l31) * Lk;

  int nt = CAUSAL ? ((q0 >> 6) + 1) : (Lk >> 6);
  for (int t = 0; t < nt - 1; ++t) {
    attn_tile<0>(Kt, Vp0, Vp1, qf, t * 64, q0, l31, hi, m, lsum, o0, o1);
    Kt += 64 * 64; Vp0 += 64; Vp1 += 64;
  }
  if (CAUSAL)
    attn_tile<1>(Kt, Vp0, Vp1, qf, (nt - 1) * 64, q0, l31, hi, m, lsum, o0, o1);
  else
    attn_tile<0>(Kt, Vp0, Vp1, qf, (nt - 1) * 64, q0, l31, hi, m, lsum, o0, o1);

  float myinv = 1.f / lsum;
  int b = bh >> 4, h = bh & 15;
#pragma unroll
  for (int r = 0; r < 16; ++r) {
    int cr = (r & 3) + 8 * (r >> 2) + 4 * hi;
    float li = __shfl(myinv, cr);
    u16* op = O + ((size_t)b * Lq + q0 + cr) * 1024 + h * 64;
    op[l31] = f2bf(o0[r] * li);
    op[32 + l31] = f2bf(o1[r] * li);
  }
}

// ---------------- launch ----------------
extern "C" void kernel_launch(void* const* d_in, const int* in_sizes, int n_in,
                              void* d_out, int out_size, void* d_ws, size_t ws_size,
                              hipStream_t stream) {
  (void)in_sizes; (void)n_in; (void)out_size;
  if (ws_size < WS_NEED) return;  // need ~105 MB scratch

  const float* x     = (const float*)d_in[0];
  const float* ctx   = (const float*)d_in[1];
  const float* g_msa = (const float*)d_in[3];
  const float* g_ca  = (const float*)d_in[4];
  const float* g_mlp = (const float*)d_in[5];
  const float* n1w = (const float*)d_in[6],  *n1b = (const float*)d_in[7];
  const float* n2w = (const float*)d_in[8],  *n2b = (const float*)d_in[9];
  const float* n3w = (const float*)d_in[10], *n3b = (const float*)d_in[11];
  const float* sa_qw = (const float*)d_in[12], *sa_kw = (const float*)d_in[14];
  const float* sa_vw = (const float*)d_in[16], *sa_pw = (const float*)d_in[18];
  const float* sa_qb = (const float*)d_in[13], *sa_kb = (const float*)d_in[15];
  const float* sa_vb = (const float*)d_in[17], *sa_pb = (const float*)d_in[19];
  const float* ca_qw = (const float*)d_in[20], *ca_qb = (const float*)d_in[21];
  const float* ca_kw = (const float*)d_in[22], *ca_kb = (const float*)d_in[23];
  const float* ca_vw = (const float*)d_in[24], *ca_vb = (const float*)d_in[25];
  const float* ca_pw = (const float*)d_in[26], *ca_pb = (const float*)d_in[27];
  const float* fc1w = (const float*)d_in[28], *fc1b = (const float*)d_in[29];
  const float* fc2w = (const float*)d_in[30], *fc2b = (const float*)d_in[31];

  char* ws = (char*)d_ws;
  float* out = (float*)d_out;
  float* tcos = (float*)(ws + OFF_TCOS);
  float* tsin = (float*)(ws + OFF_TSIN);
  u16* Hb   = (u16*)(ws + OFF_H);
  u16* QKV  = (u16*)(ws + OFF_QKV);
  u16* QR   = (u16*)(ws + OFF_QR);
  u16* KR   = (u16*)(ws + OFF_KR);
  u16* VT   = (u16*)(ws + OFF_VT);
  u16* AO   = (u16*)(ws + OFF_AO);

  // RoPE tables
  build_tab<<<dim3(128), dim3(256), 0, stream>>>(tcos, tsin);

  // fused weight/context conversion (fp32 -> bf16) into contiguous ws region
  Cvt11 ca;
  ca.s[0] = sa_qw; ca.s[1] = sa_kw; ca.s[2] = sa_vw; ca.s[3] = sa_pw;
  ca.s[4] = ca_qw; ca.s[5] = ca_kw; ca.s[6] = ca_vw; ca.s[7] = ca_pw;
  ca.s[8] = fc1w;  ca.s[9] = fc2w;  ca.s[10] = ctx;
  cvt_all<<<dim3(18432), dim3(256), 0, stream>>>(ca, (u16*)(ws + OFF_WSAQKV));
  Cp5 cp;
  cp.s[0] = sa_qb; cp.s[1] = sa_kb; cp.s[2] = sa_vb; cp.s[3] = ca_kb; cp.s[4] = ca_vb;
  copy5<<<dim3(20), dim3(256), 0, stream>>>(cp, (float*)(ws + OFF_BSAQKV));

  // ---- self-attention ----
  ln_bf16<<<dim3(NTOK), dim3(256), 0, stream>>>(x, n1w, n1b, Hb);
  gemm3<EPI_BF16><<<dim3(3072 / 256, NTOK / 256), dim3(512), 0, stream>>>(
      Hb, (u16*)(ws + OFF_WSAQKV), (float*)(ws + OFF_BSAQKV), QKV, nullptr, nullptr,
      NTOK, 3072, 1024, 1);
  rope_scatter<1, 0><<<dim3(NTOK), dim3(128), 0, stream>>>(QKV, 3072, 0, QR, tcos, tsin, LQ, QSCALE);
  rope_scatter<1, 0><<<dim3(NTOK), dim3(128), 0, stream>>>(QKV, 3072, 1024, KR, tcos, tsin, LQ, 1.0f);
  rope_scatter<0, 1><<<dim3(NTOK), dim3(128), 0, stream>>>(QKV, 3072, 2048, VT, tcos, tsin, LQ, 1.0f);
  flash_attn2<1><<<dim3(512), dim3(256), 0, stream>>>(QR, KR, VT, AO, LQ, LQ);
  gemm2<EPI_RESID><<<dim3(1024 / 128, NTOK / 128), dim3(512), 0, stream>>>(
      AO, (u16*)(ws + OFF_WSAP), sa_pb, nullptr, out, x, g_msa, NTOK, 1024, 1024, 1);

  // ---- cross-attention ----
  ln_bf16<<<dim3(NTOK), dim3(256), 0, stream>>>(out, n2w, n2b, Hb);
  gemm2<EPI_BF16><<<dim3(1024 / 128, NTOK / 128), dim3(512), 0, stream>>>(
      Hb, (u16*)(ws + OFF_WCAQ), ca_qb, (u16*)(ws + OFF_CAQ), nullptr, nullptr, nullptr,
      NTOK, 1024, 1024, 1);
  gemm2<EPI_BF16><<<dim3(2048 / 128, NCTX / 128), dim3(512), 0, stream>>>(
      (u16*)(ws + OFF_CTXB), (u16*)(ws + OFF_WCAKV), (float*)(ws + OFF_BCAKV),
      (u16*)(ws + OFF_CAKV), nullptr, nullptr, nullptr, NCTX, 2048, 1024, 1);
  rope_scatter<1, 0><<<dim3(NTOK), dim3(128), 0, stream>>>((u16*)(ws + OFF_CAQ), 1024, 0, QR, tcos, tsin, LQ, QSCALE);
  rope_scatter<1, 0><<<dim3(NCTX), dim3(128), 0, stream>>>((u16*)(ws + OFF_CAKV), 2048, 0, KR, tcos, tsin, LC, 1.0f);
  rope_scatter<0, 1><<<dim3(NCTX), dim3(128), 0, stream>>>((u16*)(ws + OFF_CAKV), 2048, 1024, VT, tcos, tsin, LC, 1.0f);
  flash_attn2<0><<<dim3(512), dim3(256), 0, stream>>>(QR, KR, VT, AO, LQ, LC);
  gemm2<EPI_RESID><<<dim3(1024 / 128, NTOK / 128), dim3(512), 0, stream>>>(
      AO, (u16*)(ws + OFF_WCAP), ca_pb, nullptr, out, out, g_ca, NTOK, 1024, 1024, 1);

  // ---- MLP ----
  ln_bf16<<<dim3(NTOK), dim3(256), 0, stream>>>(out, n3w, n3b, Hb);
  gemm3<EPI_GELU><<<dim3(4096 / 256, NTOK / 256), dim3(512), 0, stream>>>(
      Hb, (u16*)(ws + OFF_WFC1), fc1b, (u16*)(ws + OFF_U), nullptr, nullptr,
      NTOK, 4096, 1024, 1);
  // fc2: split-K x4, atomic accumulation; bias+gate pre-applied
  init_bias_gate<<<dim3(4096), dim3(256), 0, stream>>>(out, fc2b, g_mlp);
  gemm3<EPI_ATOMIC><<<dim3(1024 / 256, NTOK / 256, 4), dim3(512), 0, stream>>>(
      (u16*)(ws + OFF_U), (u16*)(ws + OFF_WFC2), nullptr, nullptr, out, g_mlp,
      NTOK, 1024, 4096, 4);
}

// Round 6
// 432.676 us; speedup vs baseline: 1.0594x; 1.0209x over previous
//
#include <hip/hip_runtime.h>
#include <math.h>

typedef __attribute__((ext_vector_type(8))) short short8;
typedef __attribute__((ext_vector_type(4))) float f32x4;
typedef __attribute__((ext_vector_type(16))) float f32x16;
typedef unsigned short u16;
typedef unsigned int u32;
typedef __attribute__((ext_vector_type(2))) u32 u32x2;
typedef __attribute__((ext_vector_type(4))) u32 u32x4;
typedef unsigned long long u64;

static constexpr int E = 1024, H = 16, LQ = 1024, LC = 512, Bn = 4, FF = 4096;
static constexpr int NTOK = Bn * LQ;   // 4096
static constexpr int NCTX = Bn * LC;   // 2048

// Q pre-scale: 1/sqrt(64) * log2(e)  (softmax runs in exp2 domain)
#define QSCALE 0.1803368801111244f
#define DEFER_THR 11.5f

// ---------------- workspace layout (bytes) ----------------
static constexpr size_t OFF_TCOS   = 0;                                    // 1024*32 f32
static constexpr size_t OFF_TSIN   = OFF_TCOS + (size_t)LQ*32*4;
static constexpr size_t OFF_BSAQKV = OFF_TSIN + (size_t)LQ*32*4;           // 3072 f32 (+ca_k/v bias after)
static constexpr size_t OFF_BCAKV  = OFF_BSAQKV + 16384;                   // 2048 f32
// contiguous bf16 weight region (order matters for cvt_all):
static constexpr size_t OFF_WSAQKV = OFF_BCAKV + 16384;                    // [3072][1024] bf16
static constexpr size_t OFF_WSAP   = OFF_WSAQKV + (size_t)3072*1024*2;     // [1024][1024]
static constexpr size_t OFF_WCAQ   = OFF_WSAP   + (size_t)1024*1024*2;
static constexpr size_t OFF_WCAKV  = OFF_WCAQ   + (size_t)1024*1024*2;     // [2048][1024]
static constexpr size_t OFF_WCAP   = OFF_WCAKV  + (size_t)2048*1024*2;
static constexpr size_t OFF_WFC1   = OFF_WCAP   + (size_t)1024*1024*2;     // [4096][1024]
static constexpr size_t OFF_WFC2   = OFF_WFC1   + (size_t)4096*1024*2;     // [1024][4096]
static constexpr size_t OFF_CTXB   = OFF_WFC2   + (size_t)1024*4096*2;     // [2048][1024] bf16
static constexpr size_t OFF_H      = OFF_CTXB   + (size_t)2048*1024*2;     // [4096][1024] bf16 (LN out)
static constexpr size_t OFF_QKV    = OFF_H      + (size_t)4096*1024*2;     // [4096][3072] bf16
static constexpr size_t OFF_CAQ    = OFF_QKV;                              // [4096][1024]
static constexpr size_t OFF_CAKV   = OFF_QKV + (size_t)4096*1024*2;        // [2048][2048]
static constexpr size_t OFF_QR     = OFF_QKV + (size_t)4096*3072*2;        // [B,H,LQ,64]
static constexpr size_t OFF_KR     = OFF_QR  + (size_t)4096*1024*2;        // [B,H,Lk,64]
static constexpr size_t OFF_VT     = OFF_KR  + (size_t)4096*1024*2;        // [B,H,64,Lk]
static constexpr size_t OFF_AO     = OFF_VT  + (size_t)4096*1024*2;        // [4096][1024] bf16
static constexpr size_t OFF_U      = OFF_QKV;                              // fc1 out [4096][4096] bf16 reuses QKV+QR
static constexpr size_t WS_NEED    = OFF_AO + (size_t)4096*1024*2;         // ~105 MB

// ---------------- helpers ----------------
static __device__ __forceinline__ float bf2f(u16 u) {
  union { u32 i; float f; } un; un.i = ((u32)u) << 16; return un.f;
}
static __device__ __forceinline__ u16 f2bf(float f) {  // RNE
  union { float f; u32 u; } un; un.f = f;
  u32 u = un.u;
  return (u16)((u + 0x7FFFu + ((u >> 16) & 1u)) >> 16);
}
static __device__ __forceinline__ u64 pack4(u16 a, u16 b, u16 c, u16 d) {
  return (u64)a | ((u64)b << 16) | ((u64)c << 32) | ((u64)d << 48);
}
static __device__ __forceinline__ f32x4 mfma16(short8 a, short8 b, f32x4 c) {
  return __builtin_amdgcn_mfma_f32_16x16x32_bf16(a, b, c, 0, 0, 0);
}
static __device__ __forceinline__ f32x16 mfma32(short8 a, short8 b, f32x16 c) {
  return __builtin_amdgcn_mfma_f32_32x32x16_bf16(a, b, c, 0, 0, 0);
}
static __device__ __forceinline__ void gload_lds16(void* lds, const void* g) {
  __builtin_amdgcn_global_load_lds(
      (const __attribute__((address_space(1))) void*)g,
      (__attribute__((address_space(3))) void*)lds, 16, 0, 0);
}
static __device__ __forceinline__ float gelu_tanh(float x) {
  float t = tanhf(0.7978845608028654f * (x + 0.044715f * x * x * x));
  return 0.5f * x * (1.0f + t);
}
static __device__ __forceinline__ u32 cvtpk_bf16(float lo, float hi) {
  u32 r;
  asm("v_cvt_pk_bf16_f32 %0, %1, %2" : "=v"(r) : "v"(lo), "v"(hi));
  return r;
}

// ---------------- small kernels ----------------
__global__ __launch_bounds__(256) void build_tab(float* __restrict__ ct, float* __restrict__ st) {
  int idx = blockIdx.x * 256 + threadIdx.x;           // 1024*32 entries
  int pos = idx >> 5, i = idx & 31;
  float inv = powf(10000.f, -(float)i * (1.f / 32.f));
  float a = (float)pos * inv;
  ct[idx] = cosf(a);
  st[idx] = sinf(a);
}

// fused fp32->bf16 conversion of all weights + context into the contiguous
// bf16 ws region. 11 segments, sizes (in 4-elem units): 8 x 262144, 2 x 1048576, 524288.
struct Cvt11 { const float* s[11]; };
__global__ __launch_bounds__(256) void cvt_all(Cvt11 a, u16* __restrict__ dst) {
  u32 gid = blockIdx.x * 256 + threadIdx.x;   // 0 .. 4718591
  u32 s, off;
  if (gid < 2097152u)      { s = gid >> 18;                        off = gid & 262143u; }
  else if (gid < 4194304u) { u32 t = gid - 2097152u; s = 8 + (t >> 20); off = t & 1048575u; }
  else                     { s = 10;                               off = gid - 4194304u; }
  float4 v = *(const float4*)(a.s[s] + (size_t)off * 4);
  *(u64*)(dst + (size_t)gid * 4) = pack4(f2bf(v.x), f2bf(v.y), f2bf(v.z), f2bf(v.w));
}

// fused bias copies: sa_q,sa_k,sa_v -> BSAQKV(+0,+1024,+2048); ca_k,ca_v -> BCAKV(+0,+1024)
struct Cp5 { const float* s[5]; };
__global__ __launch_bounds__(256) void copy5(Cp5 a, float* __restrict__ dst) {
  int gid = blockIdx.x * 256 + threadIdx.x;   // 0..5119
  int s = gid >> 10, off = gid & 1023;
  int doff = (s < 3) ? s * 1024 : 4096 + (s - 3) * 1024;
  dst[doff + off] = a.s[s][off];
}

// LN over last dim 1024, one row per block (256 threads, 4 f32 each), bf16 out.
__global__ __launch_bounds__(256) void ln_bf16(const float* __restrict__ x, const float* __restrict__ w,
                                               const float* __restrict__ b, u16* __restrict__ out) {
  __shared__ float red[4];
  int row = blockIdx.x, tid = threadIdx.x;
  const float* xr = x + (size_t)row * 1024;
  float4 v = ((const float4*)xr)[tid];
  float s = v.x + v.y + v.z + v.w;
#pragma unroll
  for (int off = 32; off; off >>= 1) s += __shfl_xor(s, off);
  if ((tid & 63) == 0) red[tid >> 6] = s;
  __syncthreads();
  float mean = (red[0] + red[1] + red[2] + red[3]) * (1.f / 1024.f);
  float dx = v.x - mean, dy = v.y - mean, dz = v.z - mean, dw = v.w - mean;
  float sq = dx * dx + dy * dy + dz * dz + dw * dw;
#pragma unroll
  for (int off = 32; off; off >>= 1) sq += __shfl_xor(sq, off);
  __syncthreads();
  if ((tid & 63) == 0) red[tid >> 6] = sq;
  __syncthreads();
  float var = (red[0] + red[1] + red[2] + red[3]) * (1.f / 1024.f);
  float rstd = rsqrtf(var + 1e-6f);
  float4 wv = ((const float4*)w)[tid];
  float4 bv = ((const float4*)b)[tid];
  u64 o = pack4(f2bf(dx * rstd * wv.x + bv.x), f2bf(dy * rstd * wv.y + bv.y),
                f2bf(dz * rstd * wv.z + bv.z), f2bf(dw * rstd * wv.w + bv.w));
  *(u64*)(out + (size_t)row * 1024 + tid * 4) = o;
}

// Fused RoPE/scatter: 3 jobs in one dispatch (blockIdx.y selects job).
// mode 0: rotate pairs (x scale), dst [B,H,Lper,64]. mode 1: transpose, dst [B,H,64,Lper].
struct RopeJob { const u16* src; u16* dst; int ld, col0, Lper, T, mode; float scale; };
struct Rope3 { RopeJob j[3]; };
__global__ __launch_bounds__(128) void rope3(Rope3 a, const float* __restrict__ cosT,
                                             const float* __restrict__ sinT) {
  RopeJob jb = a.j[blockIdx.y];
  int t = blockIdx.x;
  if (t >= jb.T) return;
  int b = t / jb.Lper, l = t - b * jb.Lper;
  int tid = threadIdx.x;
  int e0 = tid * 8;
  int h = e0 >> 6, d0 = e0 & 63;
  short8 vv = *(const short8*)(jb.src + (size_t)t * jb.ld + jb.col0 + e0);
  if (jb.mode == 0) {
    short8 ov;
#pragma unroll
    for (int j = 0; j < 4; ++j) {
      float x1 = bf2f((u16)vv[2 * j]);
      float x2 = bf2f((u16)vv[2 * j + 1]);
      int i = (d0 >> 1) + j;
      float c = cosT[l * 32 + i], s = sinT[l * 32 + i];
      ov[2 * j]     = (short)f2bf((x1 * c - x2 * s) * jb.scale);
      ov[2 * j + 1] = (short)f2bf((x1 * s + x2 * c) * jb.scale);
    }
    *(short8*)(jb.dst + (((size_t)b * H + h) * jb.Lper + l) * 64 + d0) = ov;
  } else {
#pragma unroll
    for (int m = 0; m < 8; ++m)
      jb.dst[(((size_t)b * H + h) * 64 + d0 + m) * jb.Lper + l] = (u16)vv[m];
  }
}

// ---------------- GEMM kernels: C[M,N] = A[M,K] @ W[N,K]^T + bias ----------------
enum { EPI_BF16 = 0, EPI_GELU = 1, EPI_RESID = 2 };

// gemm2: 128x128 tile, 512 threads (8 waves 2x4, 64x32/wave), 2-phase dbuf.
// Best for 256-block grids (1 block/CU): 8 waves + dbuf hide the drain.
template <int EPI>
__global__ __launch_bounds__(512, 4) void gemm2(const u16* __restrict__ A, const u16* __restrict__ W,
                                                const float* __restrict__ bias, u16* outb, float* outf,
                                                const float* res, const float* __restrict__ gate,
                                                int M, int N, int K) {
  __shared__ u16 As[2][128 * 64];
  __shared__ u16 Bs[2][128 * 64];

  int nwg = gridDim.x * gridDim.y;
  int bid = blockIdx.y * gridDim.x + blockIdx.x;
  int cpx = nwg >> 3;
  int swz = (bid & 7) * cpx + (bid >> 3);
  int bx = swz % gridDim.x;
  int by = swz / gridDim.x;
  int row0 = by * 128, col0 = bx * 128;

  int tid = threadIdx.x;
  int lane = tid & 63, wid = tid >> 6;
  int wr = wid >> 2, wc = wid & 3;  // 2x4 waves, each owns 64x32
  int lr = lane & 15, lg = lane >> 4;

  size_t a_off0, a_off1, b_off0, b_off1;
  int l_off0 = tid * 8, l_off1 = (512 + tid) * 8;
  {
    int q = tid, r = q >> 3, p = q & 7, sp = p ^ (r & 7);
    a_off0 = (size_t)(row0 + r) * K + sp * 8;
    b_off0 = (size_t)(col0 + r) * K + sp * 8;
    q = 512 + tid; r = q >> 3; p = q & 7; sp = p ^ (r & 7);
    a_off1 = (size_t)(row0 + r) * K + sp * 8;
    b_off1 = (size_t)(col0 + r) * K + sp * 8;
  }

  f32x4 acc[4][2] = {};

  const int nkt = K >> 6;
  {
    gload_lds16(&As[0][l_off0], A + a_off0);
    gload_lds16(&Bs[0][l_off0], W + b_off0);
    gload_lds16(&As[0][l_off1], A + a_off1);
    gload_lds16(&Bs[0][l_off1], W + b_off1);
  }
  __syncthreads();

  for (int kt = 0; kt < nkt; ++kt) {
    int cur = kt & 1;
    if (kt + 1 < nkt) {
      int k0 = (kt + 1) << 6;
      gload_lds16(&As[cur ^ 1][l_off0], A + a_off0 + k0);
      gload_lds16(&Bs[cur ^ 1][l_off0], W + b_off0 + k0);
      gload_lds16(&As[cur ^ 1][l_off1], A + a_off1 + k0);
      gload_lds16(&Bs[cur ^ 1][l_off1], W + b_off1 + k0);
    }
#pragma unroll
    for (int kk = 0; kk < 2; ++kk) {
      short8 af[4], bfr[2];
#pragma unroll
      for (int m = 0; m < 4; ++m) {
        int r = wr * 64 + m * 16 + lr;
        int sc = (kk * 4 + lg) ^ (r & 7);
        af[m] = *(const short8*)(&As[cur][r * 64 + sc * 8]);
      }
#pragma unroll
      for (int n = 0; n < 2; ++n) {
        int r = wc * 32 + n * 16 + lr;
        int sc = (kk * 4 + lg) ^ (r & 7);
        bfr[n] = *(const short8*)(&Bs[cur][r * 64 + sc * 8]);
      }
#pragma unroll
      for (int m = 0; m < 4; ++m)
#pragma unroll
        for (int n = 0; n < 2; ++n)
          acc[m][n] = mfma16(af[m], bfr[n], acc[m][n]);
    }
    __syncthreads();
  }

#pragma unroll
  for (int n = 0; n < 2; ++n) {
    int cg = col0 + wc * 32 + n * 16 + lr;
    float bv = bias[cg];
#pragma unroll
    for (int m = 0; m < 4; ++m) {
#pragma unroll
      for (int i = 0; i < 4; ++i) {
        int rg = row0 + wr * 64 + m * 16 + lg * 4 + i;
        float v = acc[m][n][i] + bv;
        if (EPI == EPI_BF16) {
          outb[(size_t)rg * N + cg] = f2bf(v);
        } else if (EPI == EPI_GELU) {
          outb[(size_t)rg * N + cg] = f2bf(gelu_tanh(v));
        } else {
          float r = res[(size_t)rg * N + cg];
          outf[(size_t)rg * N + cg] = r + gate[cg] * v;
        }
      }
    }
  }
}

// gemm4: m97 replica. 128x128 tile, 256 threads (4 waves 2x2, 64x64/wave,
// acc 4x4), SINGLE 32 KiB LDS buffer, 2-barrier loop. 3 blocks/CU co-resident
// hide the barrier drain (m114). Halves LDS bytes/FLOP vs gemm2's 64x32 waves.
// Use for big grids (>=3 blocks/CU): QKV, fc1.
template <int EPI>
__global__ __launch_bounds__(256, 3) void gemm4(const u16* __restrict__ A, const u16* __restrict__ W,
                                                const float* __restrict__ bias, u16* outb, float* outf,
                                                const float* res, const float* __restrict__ gate,
                                                int M, int N, int K) {
  __shared__ u16 As[128 * 64];
  __shared__ u16 Bs[128 * 64];

  int nwg = gridDim.x * gridDim.y;
  int bid = blockIdx.y * gridDim.x + blockIdx.x;
  int cpx = nwg >> 3;
  int swz = (bid & 7) * cpx + (bid >> 3);
  int bx = swz % gridDim.x;
  int by = swz / gridDim.x;
  int row0 = by * 128, col0 = bx * 128;

  int tid = threadIdx.x;
  int lane = tid & 63, wid = tid >> 6;
  int wr = wid >> 1, wc = wid & 1;      // 2x2 waves, each owns 64x64
  int lr = lane & 15, lg = lane >> 4;

  u32 aoff[4], boff[4];
  int ldso[4];
#pragma unroll
  for (int j = 0; j < 4; ++j) {
    int q = tid + j * 256;              // 16B-chunk id 0..1023
    int r = q >> 3, p = q & 7, sp = p ^ (r & 7);
    aoff[j] = (u32)(row0 + r) * (u32)K + sp * 8;
    boff[j] = (u32)(col0 + r) * (u32)K + sp * 8;
    ldso[j] = q * 8;
  }

  f32x4 acc[4][4] = {};
  const int nkt = K >> 6;

  for (int kt = 0; kt < nkt; ++kt) {
    int k0 = kt << 6;
#pragma unroll
    for (int j = 0; j < 4; ++j) {
      gload_lds16(&As[ldso[j]], A + aoff[j] + k0);
      gload_lds16(&Bs[ldso[j]], W + boff[j] + k0);
    }
    __syncthreads();                     // drains vmcnt: tile ready
#pragma unroll
    for (int kk = 0; kk < 2; ++kk) {
      short8 af[4], bf[4];
#pragma unroll
      for (int m = 0; m < 4; ++m) {
        int r = wr * 64 + m * 16 + lr;
        int sc = (kk * 4 + lg) ^ (r & 7);
        af[m] = *(const short8*)(&As[r * 64 + sc * 8]);
      }
#pragma unroll
      for (int n = 0; n < 4; ++n) {
        int r = wc * 64 + n * 16 + lr;
        int sc = (kk * 4 + lg) ^ (r & 7);
        bf[n] = *(const short8*)(&Bs[r * 64 + sc * 8]);
      }
#pragma unroll
      for (int m = 0; m < 4; ++m)
#pragma unroll
        for (int n = 0; n < 4; ++n)
          acc[m][n] = mfma16(af[m], bf[n], acc[m][n]);
    }
    __syncthreads();                     // reads done before next stage overwrites
  }

#pragma unroll
  for (int n = 0; n < 4; ++n) {
    int cg = col0 + wc * 64 + n * 16 + lr;
    float bv = bias[cg];
#pragma unroll
    for (int m = 0; m < 4; ++m) {
#pragma unroll
      for (int i = 0; i < 4; ++i) {
        int rg = row0 + wr * 64 + m * 16 + lg * 4 + i;
        float v = acc[m][n][i] + bv;
        if (EPI == EPI_BF16) {
          outb[(size_t)rg * N + cg] = f2bf(v);
        } else if (EPI == EPI_GELU) {
          outb[(size_t)rg * N + cg] = f2bf(gelu_tanh(v));
        } else {
          float r = res[(size_t)rg * N + cg];
          outf[(size_t)rg * N + cg] = r + gate[cg] * v;
        }
      }
    }
  }
}

// ---------------- flash attention, swapped-QK^T 32x32 structure ----------------
template <int MASKED>
static __device__ __forceinline__ void attn_tile(const u16* Kt, const u16* Vp0, const u16* Vp1,
                                                 const short8* qf, int kb, int q0, int l31, int hi,
                                                 float& m, float& lsum, f32x16& o0, f32x16& o1) {
  f32x16 s0 = {}, s1 = {};
  const u16* kp0 = Kt + (size_t)l31 * 64 + hi * 8;
  const u16* kp1 = Kt + (size_t)(32 + l31) * 64 + hi * 8;
  __builtin_amdgcn_s_setprio(1);
#pragma unroll
  for (int s = 0; s < 4; ++s) {
    short8 kf0 = *(const short8*)(kp0 + s * 16);
    short8 kf1 = *(const short8*)(kp1 + s * 16);
    s0 = mfma32(kf0, qf[s], s0);   // S^T[k][q]
    s1 = mfma32(kf1, qf[s], s1);
  }
  __builtin_amdgcn_s_setprio(0);
  if (MASKED) {
    int qg = q0 + l31;
#pragma unroll
    for (int r = 0; r < 16; ++r) {
      int kk = kb + (r & 3) + 8 * (r >> 2) + 4 * hi;
      if (kk > qg) s0[r] = -INFINITY;
      if (kk + 32 > qg) s1[r] = -INFINITY;
    }
  }
  float pm = -INFINITY;
#pragma unroll
  for (int r = 0; r < 16; ++r) pm = fmaxf(pm, fmaxf(s0[r], s1[r]));
  pm = fmaxf(pm, __shfl_xor(pm, 32));
  if (!__all(pm <= m + DEFER_THR)) {
    float mn = fmaxf(m, pm);
    float al = exp2f(m - mn);
    m = mn;
    lsum *= al;
#pragma unroll
    for (int r = 0; r < 16; ++r) {
      float alr = __shfl(al, (r & 3) + 8 * (r >> 2) + 4 * hi);
      o0[r] *= alr;
      o1[r] *= alr;
    }
  }
  float ts = 0.f;
#pragma unroll
  for (int r = 0; r < 16; ++r) {
    float p0 = exp2f(s0[r] - m);
    float p1 = exp2f(s1[r] - m);
    s0[r] = p0; s1[r] = p1;
    ts += p0 + p1;
  }
  ts += __shfl_xor(ts, 32);
  lsum += ts;
  auto pack8 = [&](float a0, float a1, float a2, float a3,
                   float a4, float a5, float a6, float a7) -> short8 {
    u32 c0 = cvtpk_bf16(a0, a1), c1 = cvtpk_bf16(a2, a3);
    u32 c2 = cvtpk_bf16(a4, a5), c3 = cvtpk_bf16(a6, a7);
    u32x2 r02 = __builtin_amdgcn_permlane32_swap(c0, c2, false, false);
    u32x2 r13 = __builtin_amdgcn_permlane32_swap(c1, c3, false, false);
    u32x4 w;
    w[0] = r02[0]; w[1] = r13[0]; w[2] = r02[1]; w[3] = r13[1];
    return __builtin_bit_cast(short8, w);
  };
  short8 pa0 = pack8(s0[0], s0[1], s0[2], s0[3], s0[4], s0[5], s0[6], s0[7]);
  short8 pa1 = pack8(s0[8], s0[9], s0[10], s0[11], s0[12], s0[13], s0[14], s0[15]);
  short8 pa2 = pack8(s1[0], s1[1], s1[2], s1[3], s1[4], s1[5], s1[6], s1[7]);
  short8 pa3 = pack8(s1[8], s1[9], s1[10], s1[11], s1[12], s1[13], s1[14], s1[15]);
  short8 pa[4] = {pa0, pa1, pa2, pa3};
  __builtin_amdgcn_s_setprio(1);
#pragma unroll
  for (int ks = 0; ks < 4; ++ks) {
    short8 bv0 = *(const short8*)(Vp0 + ks * 16 + hi * 8);
    short8 bv1 = *(const short8*)(Vp1 + ks * 16 + hi * 8);
    o0 = mfma32(pa[ks], bv0, o0);
    o1 = mfma32(pa[ks], bv1, o1);
  }
  __builtin_amdgcn_s_setprio(0);
}

template <int CAUSAL>
__global__ __launch_bounds__(256) void flash_attn2(const u16* __restrict__ Q, const u16* __restrict__ K,
                                                   const u16* __restrict__ Vt, u16* __restrict__ O,
                                                   int Lq, int Lk) {
  const int wid = threadIdx.x >> 6, lane = threadIdx.x & 63;
  const int l31 = lane & 31, hi = lane >> 5;
  int wg = blockIdx.x * 4 + wid;     // 4 independent waves per block, no barriers
  int bh = wg & 63;
  int qc = wg >> 6;
  if (CAUSAL) qc = (Lq >> 5) - 1 - qc;   // heavy q-chunks dispatch first
  int q0 = qc << 5;

  const u16* Qb = Q + ((size_t)bh * Lq + q0) * 64;
  const u16* Kb = K + (size_t)bh * Lk * 64;
  const u16* Vb = Vt + (size_t)bh * 64 * Lk;

  short8 qf[4];
#pragma unroll
  for (int s = 0; s < 4; ++s) qf[s] = *(const short8*)(Qb + (size_t)l31 * 64 + s * 16 + hi * 8);

  f32x16 o0 = {}, o1 = {};
  float m = -INFINITY, lsum = 0.f;

  const u16* Kt = Kb;
  const u16* Vp0 = Vb + (size_t)l31 * Lk;
  const u16* Vp1 = Vb + (size_t)(32 + l31) * Lk;

  int nt = CAUSAL ? ((q0 >> 6) + 1) : (Lk >> 6);
  for (int t = 0; t < nt - 1; ++t) {
    attn_tile<0>(Kt, Vp0, Vp1, qf, t * 64, q0, l31, hi, m, lsum, o0, o1);
    Kt += 64 * 64; Vp0 += 64; Vp1 += 64;
  }
  if (CAUSAL)
    attn_tile<1>(Kt, Vp0, Vp1, qf, (nt - 1) * 64, q0, l31, hi, m, lsum, o0, o1);
  else
    attn_tile<0>(Kt, Vp0, Vp1, qf, (nt - 1) * 64, q0, l31, hi, m, lsum, o0, o1);

  float myinv = 1.f / lsum;
  int b = bh >> 4, h = bh & 15;
#pragma unroll
  for (int r = 0; r < 16; ++r) {
    int cr = (r & 3) + 8 * (r >> 2) + 4 * hi;
    float li = __shfl(myinv, cr);
    u16* op = O + ((size_t)b * Lq + q0 + cr) * 1024 + h * 64;
    op[l31] = f2bf(o0[r] * li);
    op[32 + l31] = f2bf(o1[r] * li);
  }
}

// ---------------- launch ----------------
extern "C" void kernel_launch(void* const* d_in, const int* in_sizes, int n_in,
                              void* d_out, int out_size, void* d_ws, size_t ws_size,
                              hipStream_t stream) {
  (void)in_sizes; (void)n_in; (void)out_size;
  if (ws_size < WS_NEED) return;  // need ~105 MB scratch

  const float* x     = (const float*)d_in[0];
  const float* ctx   = (const float*)d_in[1];
  const float* g_msa = (const float*)d_in[3];
  const float* g_ca  = (const float*)d_in[4];
  const float* g_mlp = (const float*)d_in[5];
  const float* n1w = (const float*)d_in[6],  *n1b = (const float*)d_in[7];
  const float* n2w = (const float*)d_in[8],  *n2b = (const float*)d_in[9];
  const float* n3w = (const float*)d_in[10], *n3b = (const float*)d_in[11];
  const float* sa_qw = (const float*)d_in[12], *sa_kw = (const float*)d_in[14];
  const float* sa_vw = (const float*)d_in[16], *sa_pw = (const float*)d_in[18];
  const float* sa_qb = (const float*)d_in[13], *sa_kb = (const float*)d_in[15];
  const float* sa_vb = (const float*)d_in[17], *sa_pb = (const float*)d_in[19];
  const float* ca_qw = (const float*)d_in[20], *ca_qb = (const float*)d_in[21];
  const float* ca_kw = (const float*)d_in[22], *ca_kb = (const float*)d_in[23];
  const float* ca_vw = (const float*)d_in[24], *ca_vb = (const float*)d_in[25];
  const float* ca_pw = (const float*)d_in[26], *ca_pb = (const float*)d_in[27];
  const float* fc1w = (const float*)d_in[28], *fc1b = (const float*)d_in[29];
  const float* fc2w = (const float*)d_in[30], *fc2b = (const float*)d_in[31];

  char* ws = (char*)d_ws;
  float* out = (float*)d_out;
  float* tcos = (float*)(ws + OFF_TCOS);
  float* tsin = (float*)(ws + OFF_TSIN);
  u16* Hb   = (u16*)(ws + OFF_H);
  u16* QKV  = (u16*)(ws + OFF_QKV);
  u16* QR   = (u16*)(ws + OFF_QR);
  u16* KR   = (u16*)(ws + OFF_KR);
  u16* VT   = (u16*)(ws + OFF_VT);
  u16* AO   = (u16*)(ws + OFF_AO);

  // RoPE tables
  build_tab<<<dim3(128), dim3(256), 0, stream>>>(tcos, tsin);

  // fused weight/context conversion (fp32 -> bf16) into contiguous ws region
  Cvt11 ca;
  ca.s[0] = sa_qw; ca.s[1] = sa_kw; ca.s[2] = sa_vw; ca.s[3] = sa_pw;
  ca.s[4] = ca_qw; ca.s[5] = ca_kw; ca.s[6] = ca_vw; ca.s[7] = ca_pw;
  ca.s[8] = fc1w;  ca.s[9] = fc2w;  ca.s[10] = ctx;
  cvt_all<<<dim3(18432), dim3(256), 0, stream>>>(ca, (u16*)(ws + OFF_WSAQKV));
  Cp5 cp;
  cp.s[0] = sa_qb; cp.s[1] = sa_kb; cp.s[2] = sa_vb; cp.s[3] = ca_kb; cp.s[4] = ca_vb;
  copy5<<<dim3(20), dim3(256), 0, stream>>>(cp, (float*)(ws + OFF_BSAQKV));

  // ---- self-attention ----
  ln_bf16<<<dim3(NTOK), dim3(256), 0, stream>>>(x, n1w, n1b, Hb);
  gemm4<EPI_BF16><<<dim3(3072 / 128, NTOK / 128), dim3(256), 0, stream>>>(
      Hb, (u16*)(ws + OFF_WSAQKV), (float*)(ws + OFF_BSAQKV), QKV, nullptr, nullptr, nullptr,
      NTOK, 3072, 1024);
  {
    Rope3 r;
    r.j[0] = {QKV, QR, 3072, 0,    LQ, NTOK, 0, QSCALE};
    r.j[1] = {QKV, KR, 3072, 1024, LQ, NTOK, 0, 1.0f};
    r.j[2] = {QKV, VT, 3072, 2048, LQ, NTOK, 1, 1.0f};
    rope3<<<dim3(NTOK, 3), dim3(128), 0, stream>>>(r, tcos, tsin);
  }
  flash_attn2<1><<<dim3(512), dim3(256), 0, stream>>>(QR, KR, VT, AO, LQ, LQ);
  gemm2<EPI_RESID><<<dim3(1024 / 128, NTOK / 128), dim3(512), 0, stream>>>(
      AO, (u16*)(ws + OFF_WSAP), sa_pb, nullptr, out, x, g_msa, NTOK, 1024, 1024);

  // ---- cross-attention ----
  ln_bf16<<<dim3(NTOK), dim3(256), 0, stream>>>(out, n2w, n2b, Hb);
  gemm2<EPI_BF16><<<dim3(1024 / 128, NTOK / 128), dim3(512), 0, stream>>>(
      Hb, (u16*)(ws + OFF_WCAQ), ca_qb, (u16*)(ws + OFF_CAQ), nullptr, nullptr, nullptr,
      NTOK, 1024, 1024);
  gemm2<EPI_BF16><<<dim3(2048 / 128, NCTX / 128), dim3(512), 0, stream>>>(
      (u16*)(ws + OFF_CTXB), (u16*)(ws + OFF_WCAKV), (float*)(ws + OFF_BCAKV),
      (u16*)(ws + OFF_CAKV), nullptr, nullptr, nullptr, NCTX, 2048, 1024);
  {
    Rope3 r;
    r.j[0] = {(u16*)(ws + OFF_CAQ),  QR, 1024, 0,    LQ, NTOK, 0, QSCALE};
    r.j[1] = {(u16*)(ws + OFF_CAKV), KR, 2048, 0,    LC, NCTX, 0, 1.0f};
    r.j[2] = {(u16*)(ws + OFF_CAKV), VT, 2048, 1024, LC, NCTX, 1, 1.0f};
    rope3<<<dim3(NTOK, 3), dim3(128), 0, stream>>>(r, tcos, tsin);
  }
  flash_attn2<0><<<dim3(512), dim3(256), 0, stream>>>(QR, KR, VT, AO, LQ, LC);
  gemm2<EPI_RESID><<<dim3(1024 / 128, NTOK / 128), dim3(512), 0, stream>>>(
      AO, (u16*)(ws + OFF_WCAP), ca_pb, nullptr, out, out, g_ca, NTOK, 1024, 1024);

  // ---- MLP ----
  ln_bf16<<<dim3(NTOK), dim3(256), 0, stream>>>(out, n3w, n3b, Hb);
  gemm4<EPI_GELU><<<dim3(4096 / 128, NTOK / 128), dim3(256), 0, stream>>>(
      Hb, (u16*)(ws + OFF_WFC1), fc1b, (u16*)(ws + OFF_U), nullptr, nullptr, nullptr,
      NTOK, 4096, 1024);
  gemm2<EPI_RESID><<<dim3(1024 / 128, NTOK / 128), dim3(512), 0, stream>>>(
      (u16*)(ws + OFF_U), (u16*)(ws + OFF_WFC2), fc2b, nullptr, out, out, g_mlp,
      NTOK, 1024, 4096);
}

// Round 7
// 431.619 us; speedup vs baseline: 1.0620x; 1.0024x over previous
//
#include <hip/hip_runtime.h>
#include <math.h>

typedef __attribute__((ext_vector_type(8))) short short8;
typedef __attribute__((ext_vector_type(4))) float f32x4;
typedef __attribute__((ext_vector_type(16))) float f32x16;
typedef unsigned short u16;
typedef unsigned int u32;
typedef __attribute__((ext_vector_type(2))) u32 u32x2;
typedef __attribute__((ext_vector_type(4))) u32 u32x4;
typedef unsigned long long u64;

static constexpr int E = 1024, H = 16, LQ = 1024, LC = 512, Bn = 4, FF = 4096;
static constexpr int NTOK = Bn * LQ;   // 4096
static constexpr int NCTX = Bn * LC;   // 2048

// Q pre-scale: 1/sqrt(64) * log2(e)  (softmax runs in exp2 domain)
#define QSCALE 0.1803368801111244f
#define DEFER_THR 11.5f

// ---------------- workspace layout (bytes) ----------------
static constexpr size_t OFF_TCOS   = 0;                                    // 1024*32 f32
static constexpr size_t OFF_TSIN   = OFF_TCOS + (size_t)LQ*32*4;
static constexpr size_t OFF_BSAQKV = OFF_TSIN + (size_t)LQ*32*4;           // 3072 f32 (+ca_k/v bias after)
static constexpr size_t OFF_BCAKV  = OFF_BSAQKV + 16384;                   // 2048 f32
// contiguous bf16 weight region (order matters for cvt_all):
static constexpr size_t OFF_WSAQKV = OFF_BCAKV + 16384;                    // [3072][1024] bf16
static constexpr size_t OFF_WSAP   = OFF_WSAQKV + (size_t)3072*1024*2;     // [1024][1024]
static constexpr size_t OFF_WCAQ   = OFF_WSAP   + (size_t)1024*1024*2;
static constexpr size_t OFF_WCAKV  = OFF_WCAQ   + (size_t)1024*1024*2;     // [2048][1024]
static constexpr size_t OFF_WCAP   = OFF_WCAKV  + (size_t)2048*1024*2;
static constexpr size_t OFF_WFC1   = OFF_WCAP   + (size_t)1024*1024*2;     // [4096][1024]
static constexpr size_t OFF_WFC2   = OFF_WFC1   + (size_t)4096*1024*2;     // [1024][4096]
static constexpr size_t OFF_CTXB   = OFF_WFC2   + (size_t)1024*4096*2;     // [2048][1024] bf16
static constexpr size_t OFF_H      = OFF_CTXB   + (size_t)2048*1024*2;     // [4096][1024] bf16 (LN out)
static constexpr size_t OFF_QKV    = OFF_H      + (size_t)4096*1024*2;     // [4096][3072] bf16
static constexpr size_t OFF_CAQ    = OFF_QKV;                              // [4096][1024]
static constexpr size_t OFF_CAKV   = OFF_QKV + (size_t)4096*1024*2;        // [2048][2048]
static constexpr size_t OFF_QR     = OFF_QKV + (size_t)4096*3072*2;        // [B,H,LQ,64]
static constexpr size_t OFF_KR     = OFF_QR  + (size_t)4096*1024*2;        // [B,H,Lk,64]
static constexpr size_t OFF_VT     = OFF_KR  + (size_t)4096*1024*2;        // [B,H,64,Lk]
static constexpr size_t OFF_AO     = OFF_VT  + (size_t)4096*1024*2;        // [4096][1024] bf16
static constexpr size_t OFF_U      = OFF_QKV;                              // fc1 out [4096][4096] bf16 reuses QKV+QR
static constexpr size_t WS_NEED    = OFF_AO + (size_t)4096*1024*2;         // ~105 MB

// ---------------- helpers ----------------
static __device__ __forceinline__ float bf2f(u16 u) {
  union { u32 i; float f; } un; un.i = ((u32)u) << 16; return un.f;
}
static __device__ __forceinline__ u16 f2bf(float f) {  // RNE
  union { float f; u32 u; } un; un.f = f;
  u32 u = un.u;
  return (u16)((u + 0x7FFFu + ((u >> 16) & 1u)) >> 16);
}
static __device__ __forceinline__ u64 pack4(u16 a, u16 b, u16 c, u16 d) {
  return (u64)a | ((u64)b << 16) | ((u64)c << 32) | ((u64)d << 48);
}
static __device__ __forceinline__ f32x4 mfma16(short8 a, short8 b, f32x4 c) {
  return __builtin_amdgcn_mfma_f32_16x16x32_bf16(a, b, c, 0, 0, 0);
}
static __device__ __forceinline__ f32x16 mfma32(short8 a, short8 b, f32x16 c) {
  return __builtin_amdgcn_mfma_f32_32x32x16_bf16(a, b, c, 0, 0, 0);
}
static __device__ __forceinline__ void gload_lds16(void* lds, const void* g) {
  __builtin_amdgcn_global_load_lds(
      (const __attribute__((address_space(1))) void*)g,
      (__attribute__((address_space(3))) void*)lds, 16, 0, 0);
}
static __device__ __forceinline__ float gelu_tanh(float x) {
  float t = tanhf(0.7978845608028654f * (x + 0.044715f * x * x * x));
  return 0.5f * x * (1.0f + t);
}
static __device__ __forceinline__ u32 cvtpk_bf16(float lo, float hi) {
  u32 r;
  asm("v_cvt_pk_bf16_f32 %0, %1, %2" : "=v"(r) : "v"(lo), "v"(hi));
  return r;
}
#define SBAR() __builtin_amdgcn_s_barrier()

// ---------------- small kernels ----------------
__global__ __launch_bounds__(256) void build_tab(float* __restrict__ ct, float* __restrict__ st) {
  int idx = blockIdx.x * 256 + threadIdx.x;           // 1024*32 entries
  int pos = idx >> 5, i = idx & 31;
  float inv = powf(10000.f, -(float)i * (1.f / 32.f));
  float a = (float)pos * inv;
  ct[idx] = cosf(a);
  st[idx] = sinf(a);
}

// fused fp32->bf16 conversion of all weights + context into the contiguous
// bf16 ws region. 11 segments, sizes (in 4-elem units): 8 x 262144, 2 x 1048576, 524288.
struct Cvt11 { const float* s[11]; };
__global__ __launch_bounds__(256) void cvt_all(Cvt11 a, u16* __restrict__ dst) {
  u32 gid = blockIdx.x * 256 + threadIdx.x;   // 0 .. 4718591
  u32 s, off;
  if (gid < 2097152u)      { s = gid >> 18;                        off = gid & 262143u; }
  else if (gid < 4194304u) { u32 t = gid - 2097152u; s = 8 + (t >> 20); off = t & 1048575u; }
  else                     { s = 10;                               off = gid - 4194304u; }
  float4 v = *(const float4*)(a.s[s] + (size_t)off * 4);
  *(u64*)(dst + (size_t)gid * 4) = pack4(f2bf(v.x), f2bf(v.y), f2bf(v.z), f2bf(v.w));
}

// fused bias copies: sa_q,sa_k,sa_v -> BSAQKV(+0,+1024,+2048); ca_k,ca_v -> BCAKV(+0,+1024)
struct Cp5 { const float* s[5]; };
__global__ __launch_bounds__(256) void copy5(Cp5 a, float* __restrict__ dst) {
  int gid = blockIdx.x * 256 + threadIdx.x;   // 0..5119
  int s = gid >> 10, off = gid & 1023;
  int doff = (s < 3) ? s * 1024 : 4096 + (s - 3) * 1024;
  dst[doff + off] = a.s[s][off];
}

// out[row][c] += gate[c]*bias[c]  (init pass for split-K atomic GEMM)
__global__ __launch_bounds__(256) void init_bias_gate(float* __restrict__ out, const float* __restrict__ bias,
                                                      const float* __restrict__ gate) {
  int i = (blockIdx.x * 256 + threadIdx.x) * 4;
  int c = i & 1023;
  float4 o = *(float4*)(out + i);
  o.x += gate[c] * bias[c];
  o.y += gate[c + 1] * bias[c + 1];
  o.z += gate[c + 2] * bias[c + 2];
  o.w += gate[c + 3] * bias[c + 3];
  *(float4*)(out + i) = o;
}

// LN over last dim 1024, one row per block (256 threads, 4 f32 each), bf16 out.
__global__ __launch_bounds__(256) void ln_bf16(const float* __restrict__ x, const float* __restrict__ w,
                                               const float* __restrict__ b, u16* __restrict__ out) {
  __shared__ float red[4];
  int row = blockIdx.x, tid = threadIdx.x;
  const float* xr = x + (size_t)row * 1024;
  float4 v = ((const float4*)xr)[tid];
  float s = v.x + v.y + v.z + v.w;
#pragma unroll
  for (int off = 32; off; off >>= 1) s += __shfl_xor(s, off);
  if ((tid & 63) == 0) red[tid >> 6] = s;
  __syncthreads();
  float mean = (red[0] + red[1] + red[2] + red[3]) * (1.f / 1024.f);
  float dx = v.x - mean, dy = v.y - mean, dz = v.z - mean, dw = v.w - mean;
  float sq = dx * dx + dy * dy + dz * dz + dw * dw;
#pragma unroll
  for (int off = 32; off; off >>= 1) sq += __shfl_xor(sq, off);
  __syncthreads();
  if ((tid & 63) == 0) red[tid >> 6] = sq;
  __syncthreads();
  float var = (red[0] + red[1] + red[2] + red[3]) * (1.f / 1024.f);
  float rstd = rsqrtf(var + 1e-6f);
  float4 wv = ((const float4*)w)[tid];
  float4 bv = ((const float4*)b)[tid];
  u64 o = pack4(f2bf(dx * rstd * wv.x + bv.x), f2bf(dy * rstd * wv.y + bv.y),
                f2bf(dz * rstd * wv.z + bv.z), f2bf(dw * rstd * wv.w + bv.w));
  *(u64*)(out + (size_t)row * 1024 + tid * 4) = o;
}

// Fused RoPE/scatter: 3 jobs in one dispatch (blockIdx.y selects job).
// mode 0: rotate pairs (x scale), dst [B,H,Lper,64]. mode 1: transpose, dst [B,H,64,Lper].
struct RopeJob { const u16* src; u16* dst; int ld, col0, Lper, T, mode; float scale; };
struct Rope3 { RopeJob j[3]; };
__global__ __launch_bounds__(128) void rope3(Rope3 a, const float* __restrict__ cosT,
                                             const float* __restrict__ sinT) {
  RopeJob jb = a.j[blockIdx.y];
  int t = blockIdx.x;
  if (t >= jb.T) return;
  int b = t / jb.Lper, l = t - b * jb.Lper;
  int tid = threadIdx.x;
  int e0 = tid * 8;
  int h = e0 >> 6, d0 = e0 & 63;
  short8 vv = *(const short8*)(jb.src + (size_t)t * jb.ld + jb.col0 + e0);
  if (jb.mode == 0) {
    short8 ov;
#pragma unroll
    for (int j = 0; j < 4; ++j) {
      float x1 = bf2f((u16)vv[2 * j]);
      float x2 = bf2f((u16)vv[2 * j + 1]);
      int i = (d0 >> 1) + j;
      float c = cosT[l * 32 + i], s = sinT[l * 32 + i];
      ov[2 * j]     = (short)f2bf((x1 * c - x2 * s) * jb.scale);
      ov[2 * j + 1] = (short)f2bf((x1 * s + x2 * c) * jb.scale);
    }
    *(short8*)(jb.dst + (((size_t)b * H + h) * jb.Lper + l) * 64 + d0) = ov;
  } else {
#pragma unroll
    for (int m = 0; m < 8; ++m)
      jb.dst[(((size_t)b * H + h) * 64 + d0 + m) * jb.Lper + l] = (u16)vv[m];
  }
}

// ---------------- GEMM kernels: C[M,N] = A[M,K] @ W[N,K]^T + bias ----------------
enum { EPI_BF16 = 0, EPI_GELU = 1, EPI_RESID = 2, EPI_ATOMIC = 3 };

// gemm2: 128x128 tile, 512 threads (8 waves 2x4, 64x32/wave), 2-phase dbuf (proven).
template <int EPI>
__global__ __launch_bounds__(512, 4) void gemm2(const u16* __restrict__ A, const u16* __restrict__ W,
                                                const float* __restrict__ bias, u16* outb, float* outf,
                                                const float* res, const float* __restrict__ gate,
                                                int M, int N, int K, int kchunks) {
  __shared__ u16 As[2][128 * 64];
  __shared__ u16 Bs[2][128 * 64];

  int nwg = gridDim.x * gridDim.y;
  int bid = blockIdx.y * gridDim.x + blockIdx.x;
  int cpx = nwg >> 3;
  int swz = (bid & 7) * cpx + (bid >> 3);
  int bx = swz % gridDim.x;
  int by = swz / gridDim.x;
  int row0 = by * 128, col0 = bx * 128;

  const int Kc = K / kchunks;
  const int kbase = blockIdx.z * Kc;

  int tid = threadIdx.x;
  int lane = tid & 63, wid = tid >> 6;
  int wr = wid >> 2, wc = wid & 3;  // 2x4 waves, each owns 64x32
  int lr = lane & 15, lg = lane >> 4;

  size_t a_off0, a_off1, b_off0, b_off1;
  int l_off0 = tid * 8, l_off1 = (512 + tid) * 8;
  {
    int q = tid, r = q >> 3, p = q & 7, sp = p ^ (r & 7);
    a_off0 = (size_t)(row0 + r) * K + sp * 8;
    b_off0 = (size_t)(col0 + r) * K + sp * 8;
    q = 512 + tid; r = q >> 3; p = q & 7; sp = p ^ (r & 7);
    a_off1 = (size_t)(row0 + r) * K + sp * 8;
    b_off1 = (size_t)(col0 + r) * K + sp * 8;
  }

  f32x4 acc[4][2] = {};

  const int nkt = Kc >> 6;
  {
    gload_lds16(&As[0][l_off0], A + a_off0 + kbase);
    gload_lds16(&Bs[0][l_off0], W + b_off0 + kbase);
    gload_lds16(&As[0][l_off1], A + a_off1 + kbase);
    gload_lds16(&Bs[0][l_off1], W + b_off1 + kbase);
  }
  __syncthreads();

  for (int kt = 0; kt < nkt; ++kt) {
    int cur = kt & 1;
    if (kt + 1 < nkt) {
      int k0 = kbase + ((kt + 1) << 6);
      gload_lds16(&As[cur ^ 1][l_off0], A + a_off0 + k0);
      gload_lds16(&Bs[cur ^ 1][l_off0], W + b_off0 + k0);
      gload_lds16(&As[cur ^ 1][l_off1], A + a_off1 + k0);
      gload_lds16(&Bs[cur ^ 1][l_off1], W + b_off1 + k0);
    }
#pragma unroll
    for (int kk = 0; kk < 2; ++kk) {
      short8 af[4], bfr[2];
#pragma unroll
      for (int m = 0; m < 4; ++m) {
        int r = wr * 64 + m * 16 + lr;
        int sc = (kk * 4 + lg) ^ (r & 7);
        af[m] = *(const short8*)(&As[cur][r * 64 + sc * 8]);
      }
#pragma unroll
      for (int n = 0; n < 2; ++n) {
        int r = wc * 32 + n * 16 + lr;
        int sc = (kk * 4 + lg) ^ (r & 7);
        bfr[n] = *(const short8*)(&Bs[cur][r * 64 + sc * 8]);
      }
#pragma unroll
      for (int m = 0; m < 4; ++m)
#pragma unroll
        for (int n = 0; n < 2; ++n)
          acc[m][n] = mfma16(af[m], bfr[n], acc[m][n]);
    }
    __syncthreads();
  }

#pragma unroll
  for (int n = 0; n < 2; ++n) {
    int cg = col0 + wc * 32 + n * 16 + lr;
    float bv = (EPI == EPI_ATOMIC) ? 0.f : bias[cg];
#pragma unroll
    for (int m = 0; m < 4; ++m) {
#pragma unroll
      for (int i = 0; i < 4; ++i) {
        int rg = row0 + wr * 64 + m * 16 + lg * 4 + i;
        float v = acc[m][n][i] + bv;
        if (EPI == EPI_BF16) {
          outb[(size_t)rg * N + cg] = f2bf(v);
        } else if (EPI == EPI_GELU) {
          outb[(size_t)rg * N + cg] = f2bf(gelu_tanh(v));
        } else if (EPI == EPI_RESID) {
          float r = res[(size_t)rg * N + cg];
          outf[(size_t)rg * N + cg] = r + gate[cg] * v;
        } else {
          atomicAdd(&outf[(size_t)rg * N + cg], gate[cg] * v);
        }
      }
    }
  }
}

// gemm5: 256x256 tile, BK=64, 512 threads (8 waves 2x4, 128x64/wave), 128 KiB
// dbuf LDS, 8-barrier phase-interleaved K-tile (m196/m201-style, plain HIP).
// Per K-tile, 4 phases: {ds-read quadrant + stage 1 half-tile -> s_barrier ->
// setprio(1) 16 MFMA setprio(0) -> barrier}; the ONLY vmcnt(0) drain is the
// __syncthreads() ending phase 4. Hazards: stages at block kt target slot
// (kt+1)&1 (= kt-1's slot, readers passed previous drain); all reads of slot
// kt&1 covered by previous block's drain+barrier; B-frags persist in regs
// across the two A-quadrant phases.
template <int EPI>
__global__ __launch_bounds__(512, 2) void gemm5(const u16* __restrict__ A, const u16* __restrict__ W,
                                                const float* __restrict__ bias, u16* outb,
                                                int M, int N, int K) {
  __shared__ u16 As[2][256 * 64];
  __shared__ u16 Bs[2][256 * 64];

  int nwg = gridDim.x * gridDim.y;
  int bid = blockIdx.y * gridDim.x + blockIdx.x;
  int cpx = nwg >> 3;
  int swz = (bid & 7) * cpx + (bid >> 3);
  int bx = swz % gridDim.x, by = swz / gridDim.x;
  int row0 = by * 256, col0 = bx * 256;

  int tid = threadIdx.x;
  int lane = tid & 63, wid = tid >> 6;
  int wr = wid >> 2, wc = wid & 3;   // 2x4 waves, each owns 128x64
  int lr = lane & 15, lg = lane >> 4;

  // Per-thread staging geometry: each half-tile (128 rows x 64 K) = 1024
  // 16B-chunks; thread stages chunks tid and tid+512.
  int r0 = tid >> 3, p0 = tid & 7, sp0 = p0 ^ (r0 & 7);
  int q1 = tid + 512;
  int r1 = q1 >> 3, p1 = q1 & 7, sp1 = p1 ^ (r1 & 7);
  u32 ao0 = (u32)(row0 + r0) * (u32)K + sp0 * 8;
  u32 ao1 = (u32)(row0 + r1) * (u32)K + sp1 * 8;
  u32 bo0 = (u32)(col0 + r0) * (u32)K + sp0 * 8;
  u32 bo1 = (u32)(col0 + r1) * (u32)K + sp1 * 8;
  u32 hstep = (u32)K << 7;           // 128 rows
  int l0 = tid * 8, l1 = q1 * 8;     // LDS elem offsets within a half

  auto stageA = [&](int buf, int h, int k0) {
    gload_lds16(&As[buf][h * 8192 + l0], A + ao0 + h * hstep + k0);
    gload_lds16(&As[buf][h * 8192 + l1], A + ao1 + h * hstep + k0);
  };
  auto stageB = [&](int buf, int h, int k0) {
    gload_lds16(&Bs[buf][h * 8192 + l0], W + bo0 + h * hstep + k0);
    gload_lds16(&Bs[buf][h * 8192 + l1], W + bo1 + h * hstep + k0);
  };
  auto rdA = [&](int buf, int kk, int quad, short8* af) {
#pragma unroll
    for (int m = 0; m < 4; ++m) {
      int r = wr * 128 + (quad * 4 + m) * 16 + lr;
      int sc = (kk * 4 + lg) ^ (r & 7);
      af[m] = *(const short8*)(&As[buf][r * 64 + sc * 8]);
    }
  };
  auto rdB = [&](int buf, int kk, short8* bf) {
#pragma unroll
    for (int n = 0; n < 4; ++n) {
      int r = wc * 64 + n * 16 + lr;
      int sc = (kk * 4 + lg) ^ (r & 7);
      bf[n] = *(const short8*)(&Bs[buf][r * 64 + sc * 8]);
    }
  };

  f32x4 acc[8][4] = {};
  short8 af[4], bf[4];
  auto MM = [&](int mbase) {
    __builtin_amdgcn_s_setprio(1);
#pragma unroll
    for (int m = 0; m < 4; ++m)
#pragma unroll
      for (int n = 0; n < 4; ++n)
        acc[mbase + m][n] = mfma16(af[m], bf[n], acc[mbase + m][n]);
    __builtin_amdgcn_s_setprio(0);
  };

  const int nkt = K >> 6;
  // prologue: stage tile 0 fully, drain
  stageA(0, 0, 0); stageA(0, 1, 0);
  stageB(0, 0, 0); stageB(0, 1, 0);
  __syncthreads();

  for (int kt = 0; kt < nkt; ++kt) {
    int c = kt & 1, s = c ^ 1;
    int k1 = (kt + 1) << 6;
    bool pf = (kt + 1 < nkt);
    // ph1: A quad0 kk0 + B kk0; stage A-half0(kt+1)
    rdA(c, 0, 0, af); rdB(c, 0, bf);
    if (pf) stageA(s, 0, k1);
    SBAR();
    MM(0);
    SBAR();
    // ph2: A quad1 kk0 (B reused); stage A-half1
    rdA(c, 0, 1, af);
    if (pf) stageA(s, 1, k1);
    SBAR();
    MM(4);
    SBAR();
    // ph3: A quad0 kk1 + B kk1; stage B-half0
    rdA(c, 1, 0, af); rdB(c, 1, bf);
    if (pf) stageB(s, 0, k1);
    SBAR();
    MM(0);
    SBAR();
    // ph4: A quad1 kk1; stage B-half1; single drain of the K-tile
    rdA(c, 1, 1, af);
    if (pf) stageB(s, 1, k1);
    SBAR();
    MM(4);
    __syncthreads();   // vmcnt(0)+lgkmcnt(0)+barrier: tile kt+1 landed
  }

  // epilogue
#pragma unroll
  for (int n = 0; n < 4; ++n) {
    int cg = col0 + wc * 64 + n * 16 + lr;
    float bv = bias[cg];
#pragma unroll
    for (int m = 0; m < 8; ++m) {
#pragma unroll
      for (int i = 0; i < 4; ++i) {
        int rg = row0 + wr * 128 + m * 16 + lg * 4 + i;
        float v = acc[m][n][i] + bv;
        if (EPI == EPI_GELU) {
          outb[(size_t)rg * N + cg] = f2bf(gelu_tanh(v));
        } else {
          outb[(size_t)rg * N + cg] = f2bf(v);
        }
      }
    }
  }
}

// ---------------- flash attention, swapped-QK^T 32x32 structure ----------------
template <int MASKED>
static __device__ __forceinline__ void attn_tile(const u16* Kt, const u16* Vp0, const u16* Vp1,
                                                 const short8* qf, int kb, int q0, int l31, int hi,
                                                 float& m, float& lsum, f32x16& o0, f32x16& o1) {
  f32x16 s0 = {}, s1 = {};
  const u16* kp0 = Kt + (size_t)l31 * 64 + hi * 8;
  const u16* kp1 = Kt + (size_t)(32 + l31) * 64 + hi * 8;
  __builtin_amdgcn_s_setprio(1);
#pragma unroll
  for (int s = 0; s < 4; ++s) {
    short8 kf0 = *(const short8*)(kp0 + s * 16);
    short8 kf1 = *(const short8*)(kp1 + s * 16);
    s0 = mfma32(kf0, qf[s], s0);   // S^T[k][q]
    s1 = mfma32(kf1, qf[s], s1);
  }
  __builtin_amdgcn_s_setprio(0);
  if (MASKED) {
    int qg = q0 + l31;
#pragma unroll
    for (int r = 0; r < 16; ++r) {
      int kk = kb + (r & 3) + 8 * (r >> 2) + 4 * hi;
      if (kk > qg) s0[r] = -INFINITY;
      if (kk + 32 > qg) s1[r] = -INFINITY;
    }
  }
  float pm = -INFINITY;
#pragma unroll
  for (int r = 0; r < 16; ++r) pm = fmaxf(pm, fmaxf(s0[r], s1[r]));
  pm = fmaxf(pm, __shfl_xor(pm, 32));
  if (!__all(pm <= m + DEFER_THR)) {
    float mn = fmaxf(m, pm);
    float al = exp2f(m - mn);
    m = mn;
    lsum *= al;
#pragma unroll
    for (int r = 0; r < 16; ++r) {
      float alr = __shfl(al, (r & 3) + 8 * (r >> 2) + 4 * hi);
      o0[r] *= alr;
      o1[r] *= alr;
    }
  }
  float ts = 0.f;
#pragma unroll
  for (int r = 0; r < 16; ++r) {
    float p0 = exp2f(s0[r] - m);
    float p1 = exp2f(s1[r] - m);
    s0[r] = p0; s1[r] = p1;
    ts += p0 + p1;
  }
  ts += __shfl_xor(ts, 32);
  lsum += ts;
  auto pack8 = [&](float a0, float a1, float a2, float a3,
                   float a4, float a5, float a6, float a7) -> short8 {
    u32 c0 = cvtpk_bf16(a0, a1), c1 = cvtpk_bf16(a2, a3);
    u32 c2 = cvtpk_bf16(a4, a5), c3 = cvtpk_bf16(a6, a7);
    u32x2 r02 = __builtin_amdgcn_permlane32_swap(c0, c2, false, false);
    u32x2 r13 = __builtin_amdgcn_permlane32_swap(c1, c3, false, false);
    u32x4 w;
    w[0] = r02[0]; w[1] = r13[0]; w[2] = r02[1]; w[3] = r13[1];
    return __builtin_bit_cast(short8, w);
  };
  short8 pa0 = pack8(s0[0], s0[1], s0[2], s0[3], s0[4], s0[5], s0[6], s0[7]);
  short8 pa1 = pack8(s0[8], s0[9], s0[10], s0[11], s0[12], s0[13], s0[14], s0[15]);
  short8 pa2 = pack8(s1[0], s1[1], s1[2], s1[3], s1[4], s1[5], s1[6], s1[7]);
  short8 pa3 = pack8(s1[8], s1[9], s1[10], s1[11], s1[12], s1[13], s1[14], s1[15]);
  short8 pa[4] = {pa0, pa1, pa2, pa3};
  __builtin_amdgcn_s_setprio(1);
#pragma unroll
  for (int ks = 0; ks < 4; ++ks) {
    short8 bv0 = *(const short8*)(Vp0 + ks * 16 + hi * 8);
    short8 bv1 = *(const short8*)(Vp1 + ks * 16 + hi * 8);
    o0 = mfma32(pa[ks], bv0, o0);
    o1 = mfma32(pa[ks], bv1, o1);
  }
  __builtin_amdgcn_s_setprio(0);
}

template <int CAUSAL>
__global__ __launch_bounds__(256) void flash_attn2(const u16* __restrict__ Q, const u16* __restrict__ K,
                                                   const u16* __restrict__ Vt, u16* __restrict__ O,
                                                   int Lq, int Lk) {
  const int wid = threadIdx.x >> 6, lane = threadIdx.x & 63;
  const int l31 = lane & 31, hi = lane >> 5;
  int wg = blockIdx.x * 4 + wid;     // 4 independent waves per block, no barriers
  int bh = wg & 63;
  int qc = wg >> 6;
  if (CAUSAL) qc = (Lq >> 5) - 1 - qc;   // heavy q-chunks dispatch first
  int q0 = qc << 5;

  const u16* Qb = Q + ((size_t)bh * Lq + q0) * 64;
  const u16* Kb = K + (size_t)bh * Lk * 64;
  const u16* Vb = Vt + (size_t)bh * 64 * Lk;

  short8 qf[4];
#pragma unroll
  for (int s = 0; s < 4; ++s) qf[s] = *(const short8*)(Qb + (size_t)l31 * 64 + s * 16 + hi * 8);

  f32x16 o0 = {}, o1 = {};
  float m = -INFINITY, lsum = 0.f;

  const u16* Kt = Kb;
  const u16* Vp0 = Vb + (size_t)l31 * Lk;
  const u16* Vp1 = Vb + (size_t)(32 + l31) * Lk;

  int nt = CAUSAL ? ((q0 >> 6) + 1) : (Lk >> 6);
  for (int t = 0; t < nt - 1; ++t) {
    attn_tile<0>(Kt, Vp0, Vp1, qf, t * 64, q0, l31, hi, m, lsum, o0, o1);
    Kt += 64 * 64; Vp0 += 64; Vp1 += 64;
  }
  if (CAUSAL)
    attn_tile<1>(Kt, Vp0, Vp1, qf, (nt - 1) * 64, q0, l31, hi, m, lsum, o0, o1);
  else
    attn_tile<0>(Kt, Vp0, Vp1, qf, (nt - 1) * 64, q0, l31, hi, m, lsum, o0, o1);

  float myinv = 1.f / lsum;
  int b = bh >> 4, h = bh & 15;
#pragma unroll
  for (int r = 0; r < 16; ++r) {
    int cr = (r & 3) + 8 * (r >> 2) + 4 * hi;
    float li = __shfl(myinv, cr);
    u16* op = O + ((size_t)b * Lq + q0 + cr) * 1024 + h * 64;
    op[l31] = f2bf(o0[r] * li);
    op[32 + l31] = f2bf(o1[r] * li);
  }
}

// ---------------- launch ----------------
extern "C" void kernel_launch(void* const* d_in, const int* in_sizes, int n_in,
                              void* d_out, int out_size, void* d_ws, size_t ws_size,
                              hipStream_t stream) {
  (void)in_sizes; (void)n_in; (void)out_size;
  if (ws_size < WS_NEED) return;  // need ~105 MB scratch

  const float* x     = (const float*)d_in[0];
  const float* ctx   = (const float*)d_in[1];
  const float* g_msa = (const float*)d_in[3];
  const float* g_ca  = (const float*)d_in[4];
  const float* g_mlp = (const float*)d_in[5];
  const float* n1w = (const float*)d_in[6],  *n1b = (const float*)d_in[7];
  const float* n2w = (const float*)d_in[8],  *n2b = (const float*)d_in[9];
  const float* n3w = (const float*)d_in[10], *n3b = (const float*)d_in[11];
  const float* sa_qw = (const float*)d_in[12], *sa_kw = (const float*)d_in[14];
  const float* sa_vw = (const float*)d_in[16], *sa_pw = (const float*)d_in[18];
  const float* sa_qb = (const float*)d_in[13], *sa_kb = (const float*)d_in[15];
  const float* sa_vb = (const float*)d_in[17], *sa_pb = (const float*)d_in[19];
  const float* ca_qw = (const float*)d_in[20], *ca_qb = (const float*)d_in[21];
  const float* ca_kw = (const float*)d_in[22], *ca_kb = (const float*)d_in[23];
  const float* ca_vw = (const float*)d_in[24], *ca_vb = (const float*)d_in[25];
  const float* ca_pw = (const float*)d_in[26], *ca_pb = (const float*)d_in[27];
  const float* fc1w = (const float*)d_in[28], *fc1b = (const float*)d_in[29];
  const float* fc2w = (const float*)d_in[30], *fc2b = (const float*)d_in[31];

  char* ws = (char*)d_ws;
  float* out = (float*)d_out;
  float* tcos = (float*)(ws + OFF_TCOS);
  float* tsin = (float*)(ws + OFF_TSIN);
  u16* Hb   = (u16*)(ws + OFF_H);
  u16* QKV  = (u16*)(ws + OFF_QKV);
  u16* QR   = (u16*)(ws + OFF_QR);
  u16* KR   = (u16*)(ws + OFF_KR);
  u16* VT   = (u16*)(ws + OFF_VT);
  u16* AO   = (u16*)(ws + OFF_AO);

  // RoPE tables
  build_tab<<<dim3(128), dim3(256), 0, stream>>>(tcos, tsin);

  // fused weight/context conversion (fp32 -> bf16) into contiguous ws region
  Cvt11 ca;
  ca.s[0] = sa_qw; ca.s[1] = sa_kw; ca.s[2] = sa_vw; ca.s[3] = sa_pw;
  ca.s[4] = ca_qw; ca.s[5] = ca_kw; ca.s[6] = ca_vw; ca.s[7] = ca_pw;
  ca.s[8] = fc1w;  ca.s[9] = fc2w;  ca.s[10] = ctx;
  cvt_all<<<dim3(18432), dim3(256), 0, stream>>>(ca, (u16*)(ws + OFF_WSAQKV));
  Cp5 cp;
  cp.s[0] = sa_qb; cp.s[1] = sa_kb; cp.s[2] = sa_vb; cp.s[3] = ca_kb; cp.s[4] = ca_vb;
  copy5<<<dim3(20), dim3(256), 0, stream>>>(cp, (float*)(ws + OFF_BSAQKV));

  // ---- self-attention ----
  ln_bf16<<<dim3(NTOK), dim3(256), 0, stream>>>(x, n1w, n1b, Hb);
  gemm2<EPI_BF16><<<dim3(3072 / 128, NTOK / 128), dim3(512), 0, stream>>>(
      Hb, (u16*)(ws + OFF_WSAQKV), (float*)(ws + OFF_BSAQKV), QKV, nullptr, nullptr, nullptr,
      NTOK, 3072, 1024, 1);
  {
    Rope3 r;
    r.j[0] = {QKV, QR, 3072, 0,    LQ, NTOK, 0, QSCALE};
    r.j[1] = {QKV, KR, 3072, 1024, LQ, NTOK, 0, 1.0f};
    r.j[2] = {QKV, VT, 3072, 2048, LQ, NTOK, 1, 1.0f};
    rope3<<<dim3(NTOK, 3), dim3(128), 0, stream>>>(r, tcos, tsin);
  }
  flash_attn2<1><<<dim3(512), dim3(256), 0, stream>>>(QR, KR, VT, AO, LQ, LQ);
  gemm2<EPI_RESID><<<dim3(1024 / 128, NTOK / 128), dim3(512), 0, stream>>>(
      AO, (u16*)(ws + OFF_WSAP), sa_pb, nullptr, out, x, g_msa, NTOK, 1024, 1024, 1);

  // ---- cross-attention ----
  ln_bf16<<<dim3(NTOK), dim3(256), 0, stream>>>(out, n2w, n2b, Hb);
  gemm2<EPI_BF16><<<dim3(1024 / 128, NTOK / 128), dim3(512), 0, stream>>>(
      Hb, (u16*)(ws + OFF_WCAQ), ca_qb, (u16*)(ws + OFF_CAQ), nullptr, nullptr, nullptr,
      NTOK, 1024, 1024, 1);
  gemm2<EPI_BF16><<<dim3(2048 / 128, NCTX / 128), dim3(512), 0, stream>>>(
      (u16*)(ws + OFF_CTXB), (u16*)(ws + OFF_WCAKV), (float*)(ws + OFF_BCAKV),
      (u16*)(ws + OFF_CAKV), nullptr, nullptr, nullptr, NCTX, 2048, 1024, 1);
  {
    Rope3 r;
    r.j[0] = {(u16*)(ws + OFF_CAQ),  QR, 1024, 0,    LQ, NTOK, 0, QSCALE};
    r.j[1] = {(u16*)(ws + OFF_CAKV), KR, 2048, 0,    LC, NCTX, 0, 1.0f};
    r.j[2] = {(u16*)(ws + OFF_CAKV), VT, 2048, 1024, LC, NCTX, 1, 1.0f};
    rope3<<<dim3(NTOK, 3), dim3(128), 0, stream>>>(r, tcos, tsin);
  }
  flash_attn2<0><<<dim3(512), dim3(256), 0, stream>>>(QR, KR, VT, AO, LQ, LC);
  gemm2<EPI_RESID><<<dim3(1024 / 128, NTOK / 128), dim3(512), 0, stream>>>(
      AO, (u16*)(ws + OFF_WCAP), ca_pb, nullptr, out, out, g_ca, NTOK, 1024, 1024, 1);

  // ---- MLP ----
  ln_bf16<<<dim3(NTOK), dim3(256), 0, stream>>>(out, n3w, n3b, Hb);
  // fc1: 8-phase-interleaved 256^2 kernel; grid 16x16 = 256 blocks = 1/CU exactly
  gemm5<EPI_GELU><<<dim3(4096 / 256, NTOK / 256), dim3(512), 0, stream>>>(
      Hb, (u16*)(ws + OFF_WFC1), fc1b, (u16*)(ws + OFF_U), NTOK, 4096, 1024);
  // fc2: split-K x2, atomic accumulation (proven 59.6 us); bias+gate pre-applied
  init_bias_gate<<<dim3(4096), dim3(256), 0, stream>>>(out, fc2b, g_mlp);
  gemm2<EPI_ATOMIC><<<dim3(1024 / 128, NTOK / 128, 2), dim3(512), 0, stream>>>(
      (u16*)(ws + OFF_U), (u16*)(ws + OFF_WFC2), nullptr, nullptr, out, nullptr, g_mlp,
      NTOK, 1024, 4096, 2);
}

// Round 8
// 427.213 us; speedup vs baseline: 1.0729x; 1.0103x over previous
//
#include <hip/hip_runtime.h>
#include <math.h>

typedef __attribute__((ext_vector_type(8))) short short8;
typedef __attribute__((ext_vector_type(4))) float f32x4;
typedef __attribute__((ext_vector_type(16))) float f32x16;
typedef unsigned short u16;
typedef unsigned int u32;
typedef __attribute__((ext_vector_type(2))) u32 u32x2;
typedef __attribute__((ext_vector_type(4))) u32 u32x4;
typedef unsigned long long u64;

static constexpr int E = 1024, H = 16, LQ = 1024, LC = 512, Bn = 4, FF = 4096;
static constexpr int NTOK = Bn * LQ;   // 4096
static constexpr int NCTX = Bn * LC;   // 2048

// Q pre-scale: 1/sqrt(64) * log2(e)  (softmax runs in exp2 domain)
#define QSCALE 0.1803368801111244f
#define DEFER_THR 11.5f

// ---------------- workspace layout (bytes) ----------------
static constexpr size_t OFF_TCOS   = 0;                                    // 1024*32 f32
static constexpr size_t OFF_TSIN   = OFF_TCOS + (size_t)LQ*32*4;
static constexpr size_t OFF_BSAQKV = OFF_TSIN + (size_t)LQ*32*4;           // 3072 f32 (+ca_k/v bias after)
static constexpr size_t OFF_BCAKV  = OFF_BSAQKV + 16384;                   // 2048 f32
// contiguous bf16 weight region (order matters for cvt_all):
static constexpr size_t OFF_WSAQKV = OFF_BCAKV + 16384;                    // [3072][1024] bf16
static constexpr size_t OFF_WSAP   = OFF_WSAQKV + (size_t)3072*1024*2;     // [1024][1024]
static constexpr size_t OFF_WCAQ   = OFF_WSAP   + (size_t)1024*1024*2;
static constexpr size_t OFF_WCAKV  = OFF_WCAQ   + (size_t)1024*1024*2;     // [2048][1024]
static constexpr size_t OFF_WCAP   = OFF_WCAKV  + (size_t)2048*1024*2;
static constexpr size_t OFF_WFC1   = OFF_WCAP   + (size_t)1024*1024*2;     // [4096][1024]
static constexpr size_t OFF_WFC2   = OFF_WFC1   + (size_t)4096*1024*2;     // [1024][4096]
static constexpr size_t OFF_CTXB   = OFF_WFC2   + (size_t)1024*4096*2;     // [2048][1024] bf16
static constexpr size_t OFF_H      = OFF_CTXB   + (size_t)2048*1024*2;     // [4096][1024] bf16 (LN out)
static constexpr size_t OFF_QKV    = OFF_H      + (size_t)4096*1024*2;     // [4096][3072] bf16
static constexpr size_t OFF_CAQ    = OFF_QKV;                              // [4096][1024]
static constexpr size_t OFF_CAKV   = OFF_QKV + (size_t)4096*1024*2;        // [2048][2048]
static constexpr size_t OFF_QR     = OFF_QKV + (size_t)4096*3072*2;        // [B,H,LQ,64]
static constexpr size_t OFF_KR     = OFF_QR  + (size_t)4096*1024*2;        // [B,H,Lk,64]
static constexpr size_t OFF_VT     = OFF_KR  + (size_t)4096*1024*2;        // [B,H,64,Lk]
static constexpr size_t OFF_AO     = OFF_VT  + (size_t)4096*1024*2;        // [4096][1024] bf16
static constexpr size_t OFF_U      = OFF_QKV;                              // fc1 out [4096][4096] bf16 reuses QKV+QR
static constexpr size_t WS_NEED    = OFF_AO + (size_t)4096*1024*2;         // ~105 MB

// ---------------- helpers ----------------
static __device__ __forceinline__ float bf2f(u16 u) {
  union { u32 i; float f; } un; un.i = ((u32)u) << 16; return un.f;
}
static __device__ __forceinline__ u16 f2bf(float f) {  // RNE
  union { float f; u32 u; } un; un.f = f;
  u32 u = un.u;
  return (u16)((u + 0x7FFFu + ((u >> 16) & 1u)) >> 16);
}
static __device__ __forceinline__ u64 pack4(u16 a, u16 b, u16 c, u16 d) {
  return (u64)a | ((u64)b << 16) | ((u64)c << 32) | ((u64)d << 48);
}
static __device__ __forceinline__ f32x4 mfma16(short8 a, short8 b, f32x4 c) {
  return __builtin_amdgcn_mfma_f32_16x16x32_bf16(a, b, c, 0, 0, 0);
}
static __device__ __forceinline__ f32x16 mfma32(short8 a, short8 b, f32x16 c) {
  return __builtin_amdgcn_mfma_f32_32x32x16_bf16(a, b, c, 0, 0, 0);
}
static __device__ __forceinline__ void gload_lds16(void* lds, const void* g) {
  __builtin_amdgcn_global_load_lds(
      (const __attribute__((address_space(1))) void*)g,
      (__attribute__((address_space(3))) void*)lds, 16, 0, 0);
}
// gelu(x) = 0.5x(1+tanh(0.79788456(x+0.044715x^3))) = x*e/(e+1), e=exp(2z).
// Exact identity; ~8 VALU ops (vs ~30 for libm tanhf). inf/0 limits correct.
static __device__ __forceinline__ float gelu_tanh(float x) {
  float z2 = 1.5957691216057308f * (x + 0.044715f * x * x * x);
  float e = __expf(z2);
  float r = __builtin_amdgcn_rcpf(e + 1.0f);
  return x - x * r;   // x*(1 - 1/(e+1)) = x*e/(e+1)
}
static __device__ __forceinline__ u32 cvtpk_bf16(float lo, float hi) {
  u32 r;
  asm("v_cvt_pk_bf16_f32 %0, %1, %2" : "=v"(r) : "v"(lo), "v"(hi));
  return r;
}

// ---------------- small kernels ----------------
__global__ __launch_bounds__(256) void build_tab(float* __restrict__ ct, float* __restrict__ st) {
  int idx = blockIdx.x * 256 + threadIdx.x;           // 1024*32 entries
  int pos = idx >> 5, i = idx & 31;
  float inv = powf(10000.f, -(float)i * (1.f / 32.f));
  float a = (float)pos * inv;
  ct[idx] = cosf(a);
  st[idx] = sinf(a);
}

// fused fp32->bf16 conversion of all weights + context into the contiguous
// bf16 ws region. 11 segments, sizes (in 4-elem units): 8 x 262144, 2 x 1048576, 524288.
struct Cvt11 { const float* s[11]; };
__global__ __launch_bounds__(256) void cvt_all(Cvt11 a, u16* __restrict__ dst) {
  u32 gid = blockIdx.x * 256 + threadIdx.x;   // 0 .. 4718591
  u32 s, off;
  if (gid < 2097152u)      { s = gid >> 18;                        off = gid & 262143u; }
  else if (gid < 4194304u) { u32 t = gid - 2097152u; s = 8 + (t >> 20); off = t & 1048575u; }
  else                     { s = 10;                               off = gid - 4194304u; }
  float4 v = *(const float4*)(a.s[s] + (size_t)off * 4);
  *(u64*)(dst + (size_t)gid * 4) = pack4(f2bf(v.x), f2bf(v.y), f2bf(v.z), f2bf(v.w));
}

// fused bias copies: sa_q,sa_k,sa_v -> BSAQKV(+0,+1024,+2048); ca_k,ca_v -> BCAKV(+0,+1024)
struct Cp5 { const float* s[5]; };
__global__ __launch_bounds__(256) void copy5(Cp5 a, float* __restrict__ dst) {
  int gid = blockIdx.x * 256 + threadIdx.x;   // 0..5119
  int s = gid >> 10, off = gid & 1023;
  int doff = (s < 3) ? s * 1024 : 4096 + (s - 3) * 1024;
  dst[doff + off] = a.s[s][off];
}

// out[row][c] += gate[c]*bias[c]  (init pass for split-K atomic GEMM)
__global__ __launch_bounds__(256) void init_bias_gate(float* __restrict__ out, const float* __restrict__ bias,
                                                      const float* __restrict__ gate) {
  int i = (blockIdx.x * 256 + threadIdx.x) * 4;
  int c = i & 1023;
  float4 o = *(float4*)(out + i);
  o.x += gate[c] * bias[c];
  o.y += gate[c + 1] * bias[c + 1];
  o.z += gate[c + 2] * bias[c + 2];
  o.w += gate[c + 3] * bias[c + 3];
  *(float4*)(out + i) = o;
}

// LN over last dim 1024, one row per block (256 threads, 4 f32 each), bf16 out.
__global__ __launch_bounds__(256) void ln_bf16(const float* __restrict__ x, const float* __restrict__ w,
                                               const float* __restrict__ b, u16* __restrict__ out) {
  __shared__ float red[4];
  int row = blockIdx.x, tid = threadIdx.x;
  const float* xr = x + (size_t)row * 1024;
  float4 v = ((const float4*)xr)[tid];
  float s = v.x + v.y + v.z + v.w;
#pragma unroll
  for (int off = 32; off; off >>= 1) s += __shfl_xor(s, off);
  if ((tid & 63) == 0) red[tid >> 6] = s;
  __syncthreads();
  float mean = (red[0] + red[1] + red[2] + red[3]) * (1.f / 1024.f);
  float dx = v.x - mean, dy = v.y - mean, dz = v.z - mean, dw = v.w - mean;
  float sq = dx * dx + dy * dy + dz * dz + dw * dw;
#pragma unroll
  for (int off = 32; off; off >>= 1) sq += __shfl_xor(sq, off);
  __syncthreads();
  if ((tid & 63) == 0) red[tid >> 6] = sq;
  __syncthreads();
  float var = (red[0] + red[1] + red[2] + red[3]) * (1.f / 1024.f);
  float rstd = rsqrtf(var + 1e-6f);
  float4 wv = ((const float4*)w)[tid];
  float4 bv = ((const float4*)b)[tid];
  u64 o = pack4(f2bf(dx * rstd * wv.x + bv.x), f2bf(dy * rstd * wv.y + bv.y),
                f2bf(dz * rstd * wv.z + bv.z), f2bf(dw * rstd * wv.w + bv.w));
  *(u64*)(out + (size_t)row * 1024 + tid * 4) = o;
}

// Fused RoPE/scatter: 3 jobs in one dispatch (blockIdx.y selects job).
// mode 0: rotate pairs (x scale), dst [B,H,Lper,64]. mode 1: transpose, dst [B,H,64,Lper].
struct RopeJob { const u16* src; u16* dst; int ld, col0, Lper, T, mode; float scale; };
struct Rope3 { RopeJob j[3]; };
__global__ __launch_bounds__(128) void rope3(Rope3 a, const float* __restrict__ cosT,
                                             const float* __restrict__ sinT) {
  RopeJob jb = a.j[blockIdx.y];
  int t = blockIdx.x;
  if (t >= jb.T) return;
  int b = t / jb.Lper, l = t - b * jb.Lper;
  int tid = threadIdx.x;
  int e0 = tid * 8;
  int h = e0 >> 6, d0 = e0 & 63;
  short8 vv = *(const short8*)(jb.src + (size_t)t * jb.ld + jb.col0 + e0);
  if (jb.mode == 0) {
    short8 ov;
#pragma unroll
    for (int j = 0; j < 4; ++j) {
      float x1 = bf2f((u16)vv[2 * j]);
      float x2 = bf2f((u16)vv[2 * j + 1]);
      int i = (d0 >> 1) + j;
      float c = cosT[l * 32 + i], s = sinT[l * 32 + i];
      ov[2 * j]     = (short)f2bf((x1 * c - x2 * s) * jb.scale);
      ov[2 * j + 1] = (short)f2bf((x1 * s + x2 * c) * jb.scale);
    }
    *(short8*)(jb.dst + (((size_t)b * H + h) * jb.Lper + l) * 64 + d0) = ov;
  } else {
#pragma unroll
    for (int m = 0; m < 8; ++m)
      jb.dst[(((size_t)b * H + h) * 64 + d0 + m) * jb.Lper + l] = (u16)vv[m];
  }
}

// ---------------- GEMM kernels: C[M,N] = A[M,K] @ W[N,K]^T + bias ----------------
enum { EPI_BF16 = 0, EPI_GELU = 1, EPI_RESID = 2, EPI_ATOMIC = 3 };

// gemm2: 128x128 tile, 512 threads (8 waves 2x4, 64x32/wave), 2-phase dbuf (proven).
// BF16/GELU epilogues stage C through LDS so each store instruction writes
// 4 complete 256-B rows (kills partial-cache-line RMW write amplification).
template <int EPI>
__global__ __launch_bounds__(512, 4) void gemm2(const u16* __restrict__ A, const u16* __restrict__ W,
                                                const float* __restrict__ bias, u16* outb, float* outf,
                                                const float* res, const float* __restrict__ gate,
                                                int M, int N, int K, int kchunks) {
  __shared__ u16 As[2][128 * 64];
  __shared__ u16 Bs[2][128 * 64];

  int nwg = gridDim.x * gridDim.y;
  int bid = blockIdx.y * gridDim.x + blockIdx.x;
  int cpx = nwg >> 3;
  int swz = (bid & 7) * cpx + (bid >> 3);
  int bx = swz % gridDim.x;
  int by = swz / gridDim.x;
  int row0 = by * 128, col0 = bx * 128;

  const int Kc = K / kchunks;
  const int kbase = blockIdx.z * Kc;

  int tid = threadIdx.x;
  int lane = tid & 63, wid = tid >> 6;
  int wr = wid >> 2, wc = wid & 3;  // 2x4 waves, each owns 64x32
  int lr = lane & 15, lg = lane >> 4;

  size_t a_off0, a_off1, b_off0, b_off1;
  int l_off0 = tid * 8, l_off1 = (512 + tid) * 8;
  {
    int q = tid, r = q >> 3, p = q & 7, sp = p ^ (r & 7);
    a_off0 = (size_t)(row0 + r) * K + sp * 8;
    b_off0 = (size_t)(col0 + r) * K + sp * 8;
    q = 512 + tid; r = q >> 3; p = q & 7; sp = p ^ (r & 7);
    a_off1 = (size_t)(row0 + r) * K + sp * 8;
    b_off1 = (size_t)(col0 + r) * K + sp * 8;
  }

  f32x4 acc[4][2] = {};

  const int nkt = Kc >> 6;
  {
    gload_lds16(&As[0][l_off0], A + a_off0 + kbase);
    gload_lds16(&Bs[0][l_off0], W + b_off0 + kbase);
    gload_lds16(&As[0][l_off1], A + a_off1 + kbase);
    gload_lds16(&Bs[0][l_off1], W + b_off1 + kbase);
  }
  __syncthreads();

  for (int kt = 0; kt < nkt; ++kt) {
    int cur = kt & 1;
    if (kt + 1 < nkt) {
      int k0 = kbase + ((kt + 1) << 6);
      gload_lds16(&As[cur ^ 1][l_off0], A + a_off0 + k0);
      gload_lds16(&Bs[cur ^ 1][l_off0], W + b_off0 + k0);
      gload_lds16(&As[cur ^ 1][l_off1], A + a_off1 + k0);
      gload_lds16(&Bs[cur ^ 1][l_off1], W + b_off1 + k0);
    }
#pragma unroll
    for (int kk = 0; kk < 2; ++kk) {
      short8 af[4], bfr[2];
#pragma unroll
      for (int m = 0; m < 4; ++m) {
        int r = wr * 64 + m * 16 + lr;
        int sc = (kk * 4 + lg) ^ (r & 7);
        af[m] = *(const short8*)(&As[cur][r * 64 + sc * 8]);
      }
#pragma unroll
      for (int n = 0; n < 2; ++n) {
        int r = wc * 32 + n * 16 + lr;
        int sc = (kk * 4 + lg) ^ (r & 7);
        bfr[n] = *(const short8*)(&Bs[cur][r * 64 + sc * 8]);
      }
#pragma unroll
      for (int m = 0; m < 4; ++m)
#pragma unroll
        for (int n = 0; n < 2; ++n)
          acc[m][n] = mfma16(af[m], bfr[n], acc[m][n]);
    }
    __syncthreads();
  }

  if (EPI == EPI_BF16 || EPI == EPI_GELU) {
    // LDS-staged coalesced stores. As (32 KiB) = [128][128] u16 C-tile.
    u16* Ct = &As[0][0];
#pragma unroll
    for (int n = 0; n < 2; ++n) {
      int c = wc * 32 + n * 16 + lr;
      float bv = bias[col0 + c];
#pragma unroll
      for (int m = 0; m < 4; ++m) {
#pragma unroll
        for (int i = 0; i < 4; ++i) {
          int r = wr * 64 + m * 16 + lg * 4 + i;
          float v = acc[m][n][i] + bv;
          Ct[r * 128 + c] = f2bf(EPI == EPI_GELU ? gelu_tanh(v) : v);
        }
      }
    }
    __syncthreads();
    // 2048 16-B chunks; consecutive lanes cover complete 256-B rows.
#pragma unroll
    for (int j = 0; j < 4; ++j) {
      u32 q = (u32)tid + j * 512;
      u32 r = q >> 4, ck = q & 15;
      short8 v = *(const short8*)(Ct + r * 128 + ck * 8);
      *(short8*)(outb + (size_t)(row0 + r) * N + col0 + ck * 8) = v;
    }
  } else {
#pragma unroll
    for (int n = 0; n < 2; ++n) {
      int cg = col0 + wc * 32 + n * 16 + lr;
      float bv = (EPI == EPI_ATOMIC) ? 0.f : bias[cg];
#pragma unroll
      for (int m = 0; m < 4; ++m) {
#pragma unroll
        for (int i = 0; i < 4; ++i) {
          int rg = row0 + wr * 64 + m * 16 + lg * 4 + i;
          float v = acc[m][n][i] + bv;
          if (EPI == EPI_RESID) {
            float r = res[(size_t)rg * N + cg];
            outf[(size_t)rg * N + cg] = r + gate[cg] * v;
          } else {
            atomicAdd(&outf[(size_t)rg * N + cg], gate[cg] * v);
          }
        }
      }
    }
  }
}

// ---------------- flash attention, swapped-QK^T 32x32 structure ----------------
template <int MASKED>
static __device__ __forceinline__ void attn_tile(const u16* Kt, const u16* Vp0, const u16* Vp1,
                                                 const short8* qf, int kb, int q0, int l31, int hi,
                                                 float& m, float& lsum, f32x16& o0, f32x16& o1) {
  f32x16 s0 = {}, s1 = {};
  const u16* kp0 = Kt + (size_t)l31 * 64 + hi * 8;
  const u16* kp1 = Kt + (size_t)(32 + l31) * 64 + hi * 8;
  __builtin_amdgcn_s_setprio(1);
#pragma unroll
  for (int s = 0; s < 4; ++s) {
    short8 kf0 = *(const short8*)(kp0 + s * 16);
    short8 kf1 = *(const short8*)(kp1 + s * 16);
    s0 = mfma32(kf0, qf[s], s0);   // S^T[k][q]
    s1 = mfma32(kf1, qf[s], s1);
  }
  __builtin_amdgcn_s_setprio(0);
  if (MASKED) {
    int qg = q0 + l31;
#pragma unroll
    for (int r = 0; r < 16; ++r) {
      int kk = kb + (r & 3) + 8 * (r >> 2) + 4 * hi;
      if (kk > qg) s0[r] = -INFINITY;
      if (kk + 32 > qg) s1[r] = -INFINITY;
    }
  }
  float pm = -INFINITY;
#pragma unroll
  for (int r = 0; r < 16; ++r) pm = fmaxf(pm, fmaxf(s0[r], s1[r]));
  pm = fmaxf(pm, __shfl_xor(pm, 32));
  if (!__all(pm <= m + DEFER_THR)) {
    float mn = fmaxf(m, pm);
    float al = exp2f(m - mn);
    m = mn;
    lsum *= al;
#pragma unroll
    for (int r = 0; r < 16; ++r) {
      float alr = __shfl(al, (r & 3) + 8 * (r >> 2) + 4 * hi);
      o0[r] *= alr;
      o1[r] *= alr;
    }
  }
  float ts = 0.f;
#pragma unroll
  for (int r = 0; r < 16; ++r) {
    float p0 = exp2f(s0[r] - m);
    float p1 = exp2f(s1[r] - m);
    s0[r] = p0; s1[r] = p1;
    ts += p0 + p1;
  }
  ts += __shfl_xor(ts, 32);
  lsum += ts;
  auto pack8 = [&](float a0, float a1, float a2, float a3,
                   float a4, float a5, float a6, float a7) -> short8 {
    u32 c0 = cvtpk_bf16(a0, a1), c1 = cvtpk_bf16(a2, a3);
    u32 c2 = cvtpk_bf16(a4, a5), c3 = cvtpk_bf16(a6, a7);
    u32x2 r02 = __builtin_amdgcn_permlane32_swap(c0, c2, false, false);
    u32x2 r13 = __builtin_amdgcn_permlane32_swap(c1, c3, false, false);
    u32x4 w;
    w[0] = r02[0]; w[1] = r13[0]; w[2] = r02[1]; w[3] = r13[1];
    return __builtin_bit_cast(short8, w);
  };
  short8 pa0 = pack8(s0[0], s0[1], s0[2], s0[3], s0[4], s0[5], s0[6], s0[7]);
  short8 pa1 = pack8(s0[8], s0[9], s0[10], s0[11], s0[12], s0[13], s0[14], s0[15]);
  short8 pa2 = pack8(s1[0], s1[1], s1[2], s1[3], s1[4], s1[5], s1[6], s1[7]);
  short8 pa3 = pack8(s1[8], s1[9], s1[10], s1[11], s1[12], s1[13], s1[14], s1[15]);
  short8 pa[4] = {pa0, pa1, pa2, pa3};
  __builtin_amdgcn_s_setprio(1);
#pragma unroll
  for (int ks = 0; ks < 4; ++ks) {
    short8 bv0 = *(const short8*)(Vp0 + ks * 16 + hi * 8);
    short8 bv1 = *(const short8*)(Vp1 + ks * 16 + hi * 8);
    o0 = mfma32(pa[ks], bv0, o0);
    o1 = mfma32(pa[ks], bv1, o1);
  }
  __builtin_amdgcn_s_setprio(0);
}

template <int CAUSAL>
__global__ __launch_bounds__(256) void flash_attn2(const u16* __restrict__ Q, const u16* __restrict__ K,
                                                   const u16* __restrict__ Vt, u16* __restrict__ O,
                                                   int Lq, int Lk) {
  const int wid = threadIdx.x >> 6, lane = threadIdx.x & 63;
  const int l31 = lane & 31, hi = lane >> 5;
  int wg = blockIdx.x * 4 + wid;     // 4 independent waves per block, no barriers
  int bh = wg & 63;
  int qc = wg >> 6;
  if (CAUSAL) qc = (Lq >> 5) - 1 - qc;   // heavy q-chunks dispatch first
  int q0 = qc << 5;

  const u16* Qb = Q + ((size_t)bh * Lq + q0) * 64;
  const u16* Kb = K + (size_t)bh * Lk * 64;
  const u16* Vb = Vt + (size_t)bh * 64 * Lk;

  short8 qf[4];
#pragma unroll
  for (int s = 0; s < 4; ++s) qf[s] = *(const short8*)(Qb + (size_t)l31 * 64 + s * 16 + hi * 8);

  f32x16 o0 = {}, o1 = {};
  float m = -INFINITY, lsum = 0.f;

  const u16* Kt = Kb;
  const u16* Vp0 = Vb + (size_t)l31 * Lk;
  const u16* Vp1 = Vb + (size_t)(32 + l31) * Lk;

  int nt = CAUSAL ? ((q0 >> 6) + 1) : (Lk >> 6);
  for (int t = 0; t < nt - 1; ++t) {
    attn_tile<0>(Kt, Vp0, Vp1, qf, t * 64, q0, l31, hi, m, lsum, o0, o1);
    Kt += 64 * 64; Vp0 += 64; Vp1 += 64;
  }
  if (CAUSAL)
    attn_tile<1>(Kt, Vp0, Vp1, qf, (nt - 1) * 64, q0, l31, hi, m, lsum, o0, o1);
  else
    attn_tile<0>(Kt, Vp0, Vp1, qf, (nt - 1) * 64, q0, l31, hi, m, lsum, o0, o1);

  float myinv = 1.f / lsum;
  int b = bh >> 4, h = bh & 15;
#pragma unroll
  for (int r = 0; r < 16; ++r) {
    int cr = (r & 3) + 8 * (r >> 2) + 4 * hi;
    float li = __shfl(myinv, cr);
    u16* op = O + ((size_t)b * Lq + q0 + cr) * 1024 + h * 64;
    op[l31] = f2bf(o0[r] * li);
    op[32 + l31] = f2bf(o1[r] * li);
  }
}

// ---------------- launch ----------------
extern "C" void kernel_launch(void* const* d_in, const int* in_sizes, int n_in,
                              void* d_out, int out_size, void* d_ws, size_t ws_size,
                              hipStream_t stream) {
  (void)in_sizes; (void)n_in; (void)out_size;
  if (ws_size < WS_NEED) return;  // need ~105 MB scratch

  const float* x     = (const float*)d_in[0];
  const float* ctx   = (const float*)d_in[1];
  const float* g_msa = (const float*)d_in[3];
  const float* g_ca  = (const float*)d_in[4];
  const float* g_mlp = (const float*)d_in[5];
  const float* n1w = (const float*)d_in[6],  *n1b = (const float*)d_in[7];
  const float* n2w = (const float*)d_in[8],  *n2b = (const float*)d_in[9];
  const float* n3w = (const float*)d_in[10], *n3b = (const float*)d_in[11];
  const float* sa_qw = (const float*)d_in[12], *sa_kw = (const float*)d_in[14];
  const float* sa_vw = (const float*)d_in[16], *sa_pw = (const float*)d_in[18];
  const float* sa_qb = (const float*)d_in[13], *sa_kb = (const float*)d_in[15];
  const float* sa_vb = (const float*)d_in[17], *sa_pb = (const float*)d_in[19];
  const float* ca_qw = (const float*)d_in[20], *ca_qb = (const float*)d_in[21];
  const float* ca_kw = (const float*)d_in[22], *ca_kb = (const float*)d_in[23];
  const float* ca_vw = (const float*)d_in[24], *ca_vb = (const float*)d_in[25];
  const float* ca_pw = (const float*)d_in[26], *ca_pb = (const float*)d_in[27];
  const float* fc1w = (const float*)d_in[28], *fc1b = (const float*)d_in[29];
  const float* fc2w = (const float*)d_in[30], *fc2b = (const float*)d_in[31];

  char* ws = (char*)d_ws;
  float* out = (float*)d_out;
  float* tcos = (float*)(ws + OFF_TCOS);
  float* tsin = (float*)(ws + OFF_TSIN);
  u16* Hb   = (u16*)(ws + OFF_H);
  u16* QKV  = (u16*)(ws + OFF_QKV);
  u16* QR   = (u16*)(ws + OFF_QR);
  u16* KR   = (u16*)(ws + OFF_KR);
  u16* VT   = (u16*)(ws + OFF_VT);
  u16* AO   = (u16*)(ws + OFF_AO);

  // RoPE tables
  build_tab<<<dim3(128), dim3(256), 0, stream>>>(tcos, tsin);

  // fused weight/context conversion (fp32 -> bf16) into contiguous ws region
  Cvt11 ca;
  ca.s[0] = sa_qw; ca.s[1] = sa_kw; ca.s[2] = sa_vw; ca.s[3] = sa_pw;
  ca.s[4] = ca_qw; ca.s[5] = ca_kw; ca.s[6] = ca_vw; ca.s[7] = ca_pw;
  ca.s[8] = fc1w;  ca.s[9] = fc2w;  ca.s[10] = ctx;
  cvt_all<<<dim3(18432), dim3(256), 0, stream>>>(ca, (u16*)(ws + OFF_WSAQKV));
  Cp5 cp;
  cp.s[0] = sa_qb; cp.s[1] = sa_kb; cp.s[2] = sa_vb; cp.s[3] = ca_kb; cp.s[4] = ca_vb;
  copy5<<<dim3(20), dim3(256), 0, stream>>>(cp, (float*)(ws + OFF_BSAQKV));

  // ---- self-attention ----
  ln_bf16<<<dim3(NTOK), dim3(256), 0, stream>>>(x, n1w, n1b, Hb);
  gemm2<EPI_BF16><<<dim3(3072 / 128, NTOK / 128), dim3(512), 0, stream>>>(
      Hb, (u16*)(ws + OFF_WSAQKV), (float*)(ws + OFF_BSAQKV), QKV, nullptr, nullptr, nullptr,
      NTOK, 3072, 1024, 1);
  {
    Rope3 r;
    r.j[0] = {QKV, QR, 3072, 0,    LQ, NTOK, 0, QSCALE};
    r.j[1] = {QKV, KR, 3072, 1024, LQ, NTOK, 0, 1.0f};
    r.j[2] = {QKV, VT, 3072, 2048, LQ, NTOK, 1, 1.0f};
    rope3<<<dim3(NTOK, 3), dim3(128), 0, stream>>>(r, tcos, tsin);
  }
  flash_attn2<1><<<dim3(512), dim3(256), 0, stream>>>(QR, KR, VT, AO, LQ, LQ);
  gemm2<EPI_RESID><<<dim3(1024 / 128, NTOK / 128), dim3(512), 0, stream>>>(
      AO, (u16*)(ws + OFF_WSAP), sa_pb, nullptr, out, x, g_msa, NTOK, 1024, 1024, 1);

  // ---- cross-attention ----
  ln_bf16<<<dim3(NTOK), dim3(256), 0, stream>>>(out, n2w, n2b, Hb);
  gemm2<EPI_BF16><<<dim3(1024 / 128, NTOK / 128), dim3(512), 0, stream>>>(
      Hb, (u16*)(ws + OFF_WCAQ), ca_qb, (u16*)(ws + OFF_CAQ), nullptr, nullptr, nullptr,
      NTOK, 1024, 1024, 1);
  gemm2<EPI_BF16><<<dim3(2048 / 128, NCTX / 128), dim3(512), 0, stream>>>(
      (u16*)(ws + OFF_CTXB), (u16*)(ws + OFF_WCAKV), (float*)(ws + OFF_BCAKV),
      (u16*)(ws + OFF_CAKV), nullptr, nullptr, nullptr, NCTX, 2048, 1024, 1);
  {
    Rope3 r;
    r.j[0] = {(u16*)(ws + OFF_CAQ),  QR, 1024, 0,    LQ, NTOK, 0, QSCALE};
    r.j[1] = {(u16*)(ws + OFF_CAKV), KR, 2048, 0,    LC, NCTX, 0, 1.0f};
    r.j[2] = {(u16*)(ws + OFF_CAKV), VT, 2048, 1024, LC, NCTX, 1, 1.0f};
    rope3<<<dim3(NTOK, 3), dim3(128), 0, stream>>>(r, tcos, tsin);
  }
  flash_attn2<0><<<dim3(512), dim3(256), 0, stream>>>(QR, KR, VT, AO, LQ, LC);
  gemm2<EPI_RESID><<<dim3(1024 / 128, NTOK / 128), dim3(512), 0, stream>>>(
      AO, (u16*)(ws + OFF_WCAP), ca_pb, nullptr, out, out, g_ca, NTOK, 1024, 1024, 1);

  // ---- MLP ----
  ln_bf16<<<dim3(NTOK), dim3(256), 0, stream>>>(out, n3w, n3b, Hb);
  gemm2<EPI_GELU><<<dim3(4096 / 128, NTOK / 128), dim3(512), 0, stream>>>(
      Hb, (u16*)(ws + OFF_WFC1), fc1b, (u16*)(ws + OFF_U), nullptr, nullptr, nullptr,
      NTOK, 4096, 1024, 1);
  // fc2: split-K x2, atomic accumulation (R3-proven); bias+gate pre-applied
  init_bias_gate<<<dim3(4096), dim3(256), 0, stream>>>(out, fc2b, g_mlp);
  gemm2<EPI_ATOMIC><<<dim3(1024 / 128, NTOK / 128, 2), dim3(512), 0, stream>>>(
      (u16*)(ws + OFF_U), (u16*)(ws + OFF_WFC2), nullptr, nullptr, out, nullptr, g_mlp,
      NTOK, 1024, 4096, 2);
}